// Round 5
// baseline (1111.944 us; speedup 1.0000x reference)
//
#include <hip/hip_runtime.h>

#define HDIM 192
#define EPS 1e-5f

typedef __attribute__((ext_vector_type(8))) short short8;
typedef __attribute__((ext_vector_type(4))) float floatx4;

__device__ __forceinline__ float bf2f(ushort h) {
    union { uint u; float f; } c; c.u = ((uint)h) << 16; return c.f;
}
__device__ __forceinline__ ushort f2bf(float x) {
    union { float f; uint u; } c; c.f = x; return (ushort)(c.u >> 16);
}
// split fp32 into bf16 hi + bf16 lo (truncation; residual ~2^-16 relative)
__device__ __forceinline__ void splitf(float x, ushort& hi, ushort& lo) {
    hi = f2bf(x);
    lo = f2bf(x - bf2f(hi));
}

// async global -> LDS, 16 B per lane; LDS dest = wave-uniform base + lane*16
__device__ __forceinline__ void glds16(const void* g, void* l) {
    __builtin_amdgcn_global_load_lds(
        (const __attribute__((address_space(1))) uint*)g,
        (__attribute__((address_space(3))) uint*)l, 16, 0, 0);
}

// ---------------------------------------------------------------------------
// Weight prep: W[K,192] fp32 (nmat stacked) -> frag-ordered split planes.
// Per k-chunk (32 k): [plane(hi,lo)][ct(12)][lane(64)][j(8)] = 12288 ushorts.
// ---------------------------------------------------------------------------
__global__ __launch_bounds__(256) void prep_w_k(
    const float* __restrict__ W, ushort* __restrict__ Wf, int K, int nmat)
{
    int perMat = (K >> 5) * 12 * 64;
    int idx = blockIdx.x * 256 + threadIdx.x;
    if (idx >= perMat * nmat) return;
    int mat = idx / perMat;
    int r = idx - mat * perMat;
    int lane = r & 63;
    int ct = (r >> 6) % 12;
    int kc = r / (12 * 64);
    int col = ct * 16 + (lane & 15);
    int kb  = kc * 32 + (lane >> 4) * 8;
    const float* Wm = W + (size_t)mat * K * HDIM;
    ushort* base = Wf + (size_t)mat * K * HDIM * 2;
    size_t o = (size_t)kc * 12288 + (size_t)(ct * 64 + lane) * 8;
    #pragma unroll
    for (int j = 0; j < 8; ++j) {
        ushort hi, lo;
        splitf(Wm[(size_t)(kb + j) * HDIM + col], hi, lo);
        base[o + j]        = hi;
        base[o + 6144 + j] = lo;
    }
}

// ---------------------------------------------------------------------------
// split fp32 array -> bf16 hi/lo planes (8 elements per thread)
// ---------------------------------------------------------------------------
__global__ __launch_bounds__(256) void split_k(
    const float* __restrict__ src, ushort* __restrict__ hi,
    ushort* __restrict__ lo, int n8)
{
    int idx = blockIdx.x * 256 + threadIdx.x;
    if (idx >= n8) return;
    float4 v0 = ((const float4*)src)[idx * 2];
    float4 v1 = ((const float4*)src)[idx * 2 + 1];
    float v[8] = {v0.x, v0.y, v0.z, v0.w, v1.x, v1.y, v1.z, v1.w};
    ushort h[8], l[8];
    #pragma unroll
    for (int t = 0; t < 8; ++t) splitf(v[t], h[t], l[t]);
    uint4 ph, pl;
    ph.x = h[0] | ((uint)h[1] << 16); ph.y = h[2] | ((uint)h[3] << 16);
    ph.z = h[4] | ((uint)h[5] << 16); ph.w = h[6] | ((uint)h[7] << 16);
    pl.x = l[0] | ((uint)l[1] << 16); pl.y = l[2] | ((uint)l[3] << 16);
    pl.z = l[4] | ((uint)l[5] << 16); pl.w = l[6] | ((uint)l[7] << 16);
    *(uint4*)(hi + (size_t)idx * 8) = ph;
    *(uint4*)(lo + (size_t)idx * 8) = pl;
}

// ---------------------------------------------------------------------------
// MFMA GEMM: C[N,192] = A1@W1 (+ A2@W2) + bias-term, optional fused BN stats.
// Block: 256 thr / 4 waves, tile 128 rows x 192 cols.
// Pipelined K-loop: double-buffered B via global_load_lds (async), A-hi
// prefetched one chunk ahead in registers, A-lo loaded at MFMA-phase start
// and consumed only in pass 2. One barrier per chunk.
// 3-term split product: Ah*Bh + Al*Bh + Ah*Bl.
// ---------------------------------------------------------------------------
template<bool DUAL, bool RELU, bool DEG, bool STATS>
__global__ __launch_bounds__(256, 3) void gemm_mfma_k(
    const ushort* __restrict__ A1h, const ushort* __restrict__ A1l,
    const ushort* __restrict__ W1f,
    const ushort* __restrict__ A2h, const ushort* __restrict__ A2l,
    const ushort* __restrict__ W2f,
    const float* __restrict__ degf, const float* __restrict__ bias,
    float* __restrict__ C, float* __restrict__ stats, int N, int K)
{
    __shared__ ushort Bs[2][12288];   // 2 x 24 KB double buffer
    __shared__ float sstat[2][HDIM];
    const int tid  = threadIdx.x;
    const int wave = tid >> 6;
    const int lane = tid & 63;
    const int r2 = wave & 1;
    const int c2 = wave >> 1;
    const int row0 = blockIdx.x * 128 + r2 * 64;
    const int m16 = lane & 15;
    const int g4  = lane >> 4;

    if (STATS && tid < HDIM) { sstat[0][tid] = 0.f; sstat[1][tid] = 0.f; }

    // clamped row offsets (in elements) for this lane's 4 row-fragments
    int rowoff[4];
    #pragma unroll
    for (int s = 0; s < 4; ++s) {
        int rr = row0 + s * 16 + m16; if (rr >= N) rr = N - 1;
        rowoff[s] = rr * K;
    }

    floatx4 acc[4][6];
    #pragma unroll
    for (int s = 0; s < 4; ++s)
        #pragma unroll
        for (int ct = 0; ct < 6; ++ct) acc[s][ct] = (floatx4){0.f, 0.f, 0.f, 0.f};

    const int nkc = K >> 5;
    const int nch = DUAL ? nkc * 2 : nkc;   // always even (2, 6, or 12)

    auto stageB = [&](int c, int b) {
        int ph = DUAL && (c >= nkc);
        int kc = ph ? c - nkc : c;
        const ushort* src = (ph ? W2f : W1f) + (size_t)kc * 12288;
        const ushort* g = src + ((size_t)(wave * 6) * 64 + lane) * 8;
        ushort* l = &Bs[b][(size_t)(wave * 6) * 512];
        #pragma unroll
        for (int i = 0; i < 6; ++i)
            glds16(g + i * 512, l + i * 512);
    };
    auto loadAh = [&](int c, short8* ah) {
        int ph = DUAL && (c >= nkc);
        int kc = ph ? c - nkc : c;
        const ushort* Ah = ph ? A2h : A1h;
        int co = kc * 32 + g4 * 8;
        #pragma unroll
        for (int s = 0; s < 4; ++s)
            ah[s] = *(const short8*)(Ah + rowoff[s] + co);
    };
    auto bfrag = [&](int b, int ct, int plane) -> short8 {
        return *(const short8*)&Bs[b][plane * 6144 + (c2 * 6 + ct) * 512 + lane * 8];
    };
    auto mfmaPhase = [&](int c, int b, short8* ah) {
        int ph = DUAL && (c >= nkc);
        int kc = ph ? c - nkc : c;
        const ushort* Al = ph ? A2l : A1l;
        int co = kc * 32 + g4 * 8;
        short8 al[4];
        #pragma unroll
        for (int s = 0; s < 4; ++s)
            al[s] = *(const short8*)(Al + rowoff[s] + co);
        // pass 1: hi*hi (covers al load latency)
        #pragma unroll
        for (int ct = 0; ct < 6; ++ct) {
            short8 bh = bfrag(b, ct, 0);
            #pragma unroll
            for (int s = 0; s < 4; ++s)
                acc[s][ct] = __builtin_amdgcn_mfma_f32_16x16x32_bf16(ah[s], bh, acc[s][ct], 0, 0, 0);
        }
        // pass 2: lo*hi + hi*lo
        #pragma unroll
        for (int ct = 0; ct < 6; ++ct) {
            short8 bh = bfrag(b, ct, 0);
            short8 bl = bfrag(b, ct, 1);
            #pragma unroll
            for (int s = 0; s < 4; ++s) {
                acc[s][ct] = __builtin_amdgcn_mfma_f32_16x16x32_bf16(al[s], bh, acc[s][ct], 0, 0, 0);
                acc[s][ct] = __builtin_amdgcn_mfma_f32_16x16x32_bf16(ah[s], bl, acc[s][ct], 0, 0, 0);
            }
        }
    };

    short8 aA[4], aB[4];
    stageB(0, 0);
    loadAh(0, aA);
    for (int cc = 0; cc < nch; cc += 2) {
        __syncthreads();                       // drain B[cc] (+A prefetch)
        if (cc + 1 < nch) { stageB(cc + 1, 1); loadAh(cc + 1, aB); }
        mfmaPhase(cc, 0, aA);
        __syncthreads();                       // drain B[cc+1]
        if (cc + 2 < nch) { stageB(cc + 2, 0); loadAh(cc + 2, aA); }
        if (cc + 1 < nch) mfmaPhase(cc + 1, 1, aB);
    }

    // epilogue: C/D layout col=lane&15, row=(lane>>4)*4+reg  [m89]
    #pragma unroll
    for (int ct = 0; ct < 6; ++ct) {
        int col = c2 * 96 + ct * 16 + m16;
        float bv = bias ? bias[col] : 0.f;
        float lsum = 0.f, lsq = 0.f;
        #pragma unroll
        for (int s = 0; s < 4; ++s) {
            #pragma unroll
            for (int reg = 0; reg < 4; ++reg) {
                int rr = row0 + s * 16 + g4 * 4 + reg;
                if (rr < N) {
                    float v = acc[s][ct][reg] + (DEG ? degf[rr] * bv : bv);
                    if (STATS) { lsum += v; lsq += v * v; }
                    if (RELU) v = fmaxf(v, 0.f);
                    C[(size_t)rr * HDIM + col] = v;
                }
            }
        }
        if (STATS) {
            lsum += __shfl_xor(lsum, 16); lsum += __shfl_xor(lsum, 32);
            lsq  += __shfl_xor(lsq, 16);  lsq  += __shfl_xor(lsq, 32);
            if (g4 == 0) {
                atomicAdd(&sstat[0][col], lsum);
                atomicAdd(&sstat[1][col], lsq);
            }
        }
    }
    if (STATS) {
        __syncthreads();
        if (tid < HDIM) {
            atomicAdd(&stats[tid], sstat[0][tid]);
            atomicAdd(&stats[HDIM + tid], sstat[1][tid]);
        }
    }
}

// ---------------------------------------------------------------------------
// CSR construction from edge_dst
// ---------------------------------------------------------------------------
__global__ __launch_bounds__(256) void hist_k(
    const int* __restrict__ dst, int* __restrict__ deg, int E)
{
    int e = blockIdx.x * 256 + threadIdx.x;
    if (e < E) atomicAdd(&deg[dst[e]], 1);
}

__global__ __launch_bounds__(256) void block_sum_k(
    const int* __restrict__ deg, int* __restrict__ bsum, int N)
{
    __shared__ int s[256];
    int t = threadIdx.x;
    int n = blockIdx.x * 256 + t;
    s[t] = (n < N) ? deg[n] : 0;
    __syncthreads();
    for (int off = 128; off > 0; off >>= 1) {
        if (t < off) s[t] += s[t + off];
        __syncthreads();
    }
    if (t == 0) bsum[blockIdx.x] = s[0];
}

__global__ __launch_bounds__(512) void scan_bsum_k(int* __restrict__ bsum, int nb)
{
    __shared__ int s[512];
    int t = threadIdx.x;
    int v = (t < nb) ? bsum[t] : 0;
    s[t] = v;
    __syncthreads();
    for (int off = 1; off < 512; off <<= 1) {
        int u = (t >= off) ? s[t - off] : 0;
        __syncthreads();
        s[t] += u;
        __syncthreads();
    }
    if (t < nb) bsum[t] = s[t] - v;   // exclusive
}

__global__ __launch_bounds__(256) void row_ptr_k(
    const int* __restrict__ deg, const int* __restrict__ bsum,
    int* __restrict__ row_ptr, int* __restrict__ cursor,
    float* __restrict__ degf, int N, int E)
{
    __shared__ int s[256];
    int t = threadIdx.x;
    int n = blockIdx.x * 256 + t;
    int v = (n < N) ? deg[n] : 0;
    s[t] = v;
    __syncthreads();
    for (int off = 1; off < 256; off <<= 1) {
        int u = (t >= off) ? s[t - off] : 0;
        __syncthreads();
        s[t] += u;
        __syncthreads();
    }
    int ex = s[t] - v + bsum[blockIdx.x];
    if (n < N) {
        row_ptr[n] = ex;
        cursor[n]  = ex;
        degf[n]    = (float)v;
    }
    if (blockIdx.x == 0 && t == 0) row_ptr[N] = E;
}

__global__ __launch_bounds__(256) void fill_k(
    const int* __restrict__ src, const int* __restrict__ dst,
    int* __restrict__ cursor, int* __restrict__ col, int E)
{
    int e = blockIdx.x * 256 + threadIdx.x;
    if (e < E) {
        int p = atomicAdd(&cursor[dst[e]], 1);
        col[p] = src[e];
    }
}

// ---------------------------------------------------------------------------
// gather on split planes: g[n] = sum_{j} (hi+lo)[col[j]]; output re-split.
// ---------------------------------------------------------------------------
__global__ __launch_bounds__(256) void gather_split_k(
    const ushort* __restrict__ xh, const ushort* __restrict__ xl,
    const int* __restrict__ row_ptr, const int* __restrict__ col,
    ushort* __restrict__ gh, ushort* __restrict__ gl, int N, int K)
{
    int WQ = K >> 3;
    int idx = blockIdx.x * 256 + threadIdx.x;
    if (idx >= N * WQ) return;
    int n = idx / WQ;
    int q = (idx - n * WQ) * 8;
    int j0 = row_ptr[n], j1 = row_ptr[n + 1];
    float acc[8] = {0.f,0.f,0.f,0.f,0.f,0.f,0.f,0.f};
    for (int j = j0; j < j1; ++j) {
        int s = col[j];
        uint4 hv = *(const uint4*)(xh + (size_t)s * K + q);
        uint4 lv = *(const uint4*)(xl + (size_t)s * K + q);
        uint hu[4] = {hv.x, hv.y, hv.z, hv.w};
        uint lu[4] = {lv.x, lv.y, lv.z, lv.w};
        #pragma unroll
        for (int t = 0; t < 4; ++t) {
            acc[2*t]   += bf2f((ushort)(hu[t] & 0xffffu)) + bf2f((ushort)(lu[t] & 0xffffu));
            acc[2*t+1] += bf2f((ushort)(hu[t] >> 16))     + bf2f((ushort)(lu[t] >> 16));
        }
    }
    ushort oh[8], ol[8];
    #pragma unroll
    for (int t = 0; t < 8; ++t) splitf(acc[t], oh[t], ol[t]);
    uint4 ph, pl;
    ph.x = oh[0] | ((uint)oh[1] << 16); ph.y = oh[2] | ((uint)oh[3] << 16);
    ph.z = oh[4] | ((uint)oh[5] << 16); ph.w = oh[6] | ((uint)oh[7] << 16);
    pl.x = ol[0] | ((uint)ol[1] << 16); pl.y = ol[2] | ((uint)ol[3] << 16);
    pl.z = ol[4] | ((uint)ol[5] << 16); pl.w = ol[6] | ((uint)ol[7] << 16);
    *(uint4*)(gh + (size_t)n * K + q) = ph;
    *(uint4*)(gl + (size_t)n * K + q) = pl;
}

// ---------------------------------------------------------------------------
// batchnorm finalize + apply
// ---------------------------------------------------------------------------
__global__ void bn_finalize_k(const float* __restrict__ sums,
                              const float* __restrict__ gamma,
                              const float* __restrict__ beta,
                              float* __restrict__ ss, float invN)
{
    int c = threadIdx.x;
    float mu  = sums[c] * invN;
    float var = sums[HDIM + c] * invN - mu * mu;
    float sc  = gamma[c] * rsqrtf(var + EPS);
    ss[c]        = sc;
    ss[HDIM + c] = beta[c] - mu * sc;
}

__global__ __launch_bounds__(256) void bn_apply_split_k(
    const float* __restrict__ h, const float* __restrict__ ss,
    ushort* __restrict__ xh, ushort* __restrict__ xl, int N)
{
    int idx = blockIdx.x * 256 + threadIdx.x;   // over N*24
    if (idx >= N * 24) return;
    int q = (idx % 24) * 8;
    float4 v0 = ((const float4*)h)[idx * 2];
    float4 v1 = ((const float4*)h)[idx * 2 + 1];
    float v[8] = {v0.x, v0.y, v0.z, v0.w, v1.x, v1.y, v1.z, v1.w};
    ushort oh[8], ol[8];
    #pragma unroll
    for (int t = 0; t < 8; ++t) {
        float r = fmaxf(v[t] * ss[q + t] + ss[HDIM + q + t], 0.f);
        splitf(r, oh[t], ol[t]);
    }
    uint4 ph, pl;
    ph.x = oh[0] | ((uint)oh[1] << 16); ph.y = oh[2] | ((uint)oh[3] << 16);
    ph.z = oh[4] | ((uint)oh[5] << 16); ph.w = oh[6] | ((uint)oh[7] << 16);
    pl.x = ol[0] | ((uint)ol[1] << 16); pl.y = ol[2] | ((uint)ol[3] << 16);
    pl.z = ol[4] | ((uint)ol[5] << 16); pl.w = ol[6] | ((uint)ol[7] << 16);
    *(uint4*)(xh + (size_t)idx * 8) = ph;
    *(uint4*)(xl + (size_t)idx * 8) = pl;
}

// ---------------------------------------------------------------------------
// pool over contiguous per-graph row ranges (batch sorted)
// ---------------------------------------------------------------------------
__global__ __launch_bounds__(256) void init_start_k(int* __restrict__ start, int G, int N)
{
    int g = blockIdx.x * 256 + threadIdx.x;
    if (g <= G) start[g] = N;
}

__global__ __launch_bounds__(256) void bound_k(
    const int* __restrict__ batch, int* __restrict__ start, int N)
{
    int n = blockIdx.x * 256 + threadIdx.x;
    if (n >= N) return;
    int b  = batch[n];
    int bp = (n == 0) ? -1 : batch[n - 1];
    for (int g = bp + 1; g <= b; ++g) start[g] = n;
}

__global__ __launch_bounds__(192) void pool_k(
    const ushort* __restrict__ xh, const ushort* __restrict__ xl,
    const int* __restrict__ start, float* __restrict__ gout, int G)
{
    int g = blockIdx.x;
    int c = threadIdx.x;
    int r0 = start[g], r1 = start[g + 1];
    float s = 0.f;
    for (int r = r0; r < r1; ++r) {
        size_t o = (size_t)r * HDIM + c;
        s += bf2f(xh[o]) + bf2f(xl[o]);
    }
    float cnt = (float)(r1 - r0);
    gout[(size_t)g * HDIM + c] = s / fmaxf(cnt, 1.f);
}

// ---------------------------------------------------------------------------
__global__ __launch_bounds__(64) void out_dot_k(
    const float* __restrict__ g2, const float* __restrict__ Wout,
    const float* __restrict__ bout, float* __restrict__ out, int G)
{
    int gi = blockIdx.x;
    int t = threadIdx.x;
    const float* r = g2 + (size_t)gi * HDIM;
    float s = r[t] * Wout[t] + r[t + 64] * Wout[t + 64] + r[t + 128] * Wout[t + 128];
    #pragma unroll
    for (int off = 32; off > 0; off >>= 1) s += __shfl_down(s, off, 64);
    if (t == 0) out[gi] = s + bout[0];
}

// ---------------------------------------------------------------------------
extern "C" void kernel_launch(void* const* d_in, const int* in_sizes, int n_in,
                              void* d_out, int out_size, void* d_ws, size_t ws_size,
                              hipStream_t stream)
{
    const float* x      = (const float*)d_in[0];
    const int*   esrc   = (const int*)d_in[1];
    const int*   edst   = (const int*)d_in[2];
    const int*   batch  = (const int*)d_in[3];
    const float* Wrel0  = (const float*)d_in[4];
    const float* brel0  = (const float*)d_in[5];
    const float* Wroot0 = (const float*)d_in[6];
    const float* Wrel   = (const float*)d_in[7];
    const float* brel   = (const float*)d_in[8];
    const float* Wroot  = (const float*)d_in[9];
    const float* gamma  = (const float*)d_in[10];
    const float* beta   = (const float*)d_in[11];
    const float* Wh1    = (const float*)d_in[12];
    const float* bh1    = (const float*)d_in[13];
    const float* Wh2    = (const float*)d_in[14];
    const float* bh2    = (const float*)d_in[15];
    const float* Wout   = (const float*)d_in[16];
    const float* bout   = (const float*)d_in[17];
    float* out = (float*)d_out;

    const int N  = in_sizes[3];           // 100000
    const int E  = in_sizes[1];           // 400000
    const int K0 = in_sizes[0] / N;       // 32
    const int G  = out_size;              // 2000
    const int nBlocks = (N + 255) / 256;

    char* p = (char*)d_ws;
    auto carve = [&](size_t bytes) -> void* {
        void* r = (void*)p; p += (bytes + 255) & ~(size_t)255; return r;
    };
    float*  bufa  = (float*) carve((size_t)N * HDIM * 4);
    ushort* xh    = (ushort*)carve((size_t)N * HDIM * 2);
    ushort* xl    = (ushort*)carve((size_t)N * HDIM * 2);
    ushort* gh    = (ushort*)carve((size_t)N * HDIM * 2);
    ushort* gl    = (ushort*)carve((size_t)N * HDIM * 2);
    float*  gsum  = (float*) carve((size_t)G * HDIM * 4);
    float*  g1    = (float*) carve((size_t)G * HDIM * 4);
    float*  g2    = (float*) carve((size_t)G * HDIM * 4);
    ushort* gsh   = (ushort*)carve((size_t)G * HDIM * 2);
    ushort* gsl   = (ushort*)carve((size_t)G * HDIM * 2);
    ushort* g1h   = (ushort*)carve((size_t)G * HDIM * 2);
    ushort* g1l   = (ushort*)carve((size_t)G * HDIM * 2);
    float*  bnsums= (float*) carve(2 * HDIM * 4);
    float*  bnss  = (float*) carve(2 * HDIM * 4);
    float*  degf  = (float*) carve((size_t)N * 4);
    int*    deg   = (int*)   carve((size_t)N * 4);
    int*    row_ptr=(int*)   carve((size_t)(N + 1) * 4);
    int*    cursor= (int*)   carve((size_t)N * 4);
    int*    col   = (int*)   carve((size_t)E * 4);
    int*    bsum  = (int*)   carve((size_t)nBlocks * 4);
    int*    start = (int*)   carve((size_t)(G + 1) * 4);
    ushort* Wrel0f= (ushort*)carve((size_t)K0 * HDIM * 2 * 2);
    ushort* Wroot0f=(ushort*)carve((size_t)K0 * HDIM * 2 * 2);
    ushort* Wrelf = (ushort*)carve((size_t)3 * HDIM * HDIM * 2 * 2);
    ushort* Wrootf= (ushort*)carve((size_t)3 * HDIM * HDIM * 2 * 2);
    ushort* Wh1f  = (ushort*)carve((size_t)HDIM * HDIM * 2 * 2);
    ushort* Wh2f  = (ushort*)carve((size_t)HDIM * HDIM * 2 * 2);

    dim3 b256(256);
    const int eBlocks = (E + 255) / 256;
    const int gemmN = (N + 127) / 128;
    const int gemmG = (G + 127) / 128;

    // ---- weight prep (frag-ordered hi/lo split)
    {
        int t0 = (K0 >> 5) * 12 * 64;
        int t1 = (HDIM >> 5) * 12 * 64;
        prep_w_k<<<(t0 + 255) / 256, b256, 0, stream>>>(Wrel0,  Wrel0f,  K0, 1);
        prep_w_k<<<(t0 + 255) / 256, b256, 0, stream>>>(Wroot0, Wroot0f, K0, 1);
        prep_w_k<<<(3 * t1 + 255) / 256, b256, 0, stream>>>(Wrel,  Wrelf,  HDIM, 3);
        prep_w_k<<<(3 * t1 + 255) / 256, b256, 0, stream>>>(Wroot, Wrootf, HDIM, 3);
        prep_w_k<<<(t1 + 255) / 256, b256, 0, stream>>>(Wh1, Wh1f, HDIM, 1);
        prep_w_k<<<(t1 + 255) / 256, b256, 0, stream>>>(Wh2, Wh2f, HDIM, 1);
    }
    split_k<<<((N * K0 / 8) + 255) / 256, b256, 0, stream>>>(x, xh, xl, N * K0 / 8);

    // ---- CSR build
    hipMemsetAsync(deg, 0, N * sizeof(int), stream);
    hist_k<<<eBlocks, b256, 0, stream>>>(edst, deg, E);
    block_sum_k<<<nBlocks, b256, 0, stream>>>(deg, bsum, N);
    scan_bsum_k<<<1, dim3(512), 0, stream>>>(bsum, nBlocks);
    row_ptr_k<<<nBlocks, b256, 0, stream>>>(deg, bsum, row_ptr, cursor, degf, N, E);
    fill_k<<<eBlocks, b256, 0, stream>>>(esrc, edst, cursor, col, E);

    // ---- graph boundaries for pooling
    init_start_k<<<(G + 256) / 256, b256, 0, stream>>>(start, G, N);
    bound_k<<<nBlocks, b256, 0, stream>>>(batch, start, N);

    // ---- layers
    for (int l = 0; l < 4; ++l) {
        const int K = (l == 0) ? K0 : HDIM;
        const ushort* Wrf = (l == 0) ? Wrel0f  : Wrelf  + (size_t)(l - 1) * HDIM * HDIM * 2;
        const ushort* Wtf = (l == 0) ? Wroot0f : Wrootf + (size_t)(l - 1) * HDIM * HDIM * 2;
        const float*  br  = (l == 0) ? brel0   : brel   + (size_t)(l - 1) * HDIM;

        int gthreads = N * (K >> 3);
        gather_split_k<<<(gthreads + 255) / 256, b256, 0, stream>>>(
            xh, xl, row_ptr, col, gh, gl, N, K);
        hipMemsetAsync(bnsums, 0, 2 * HDIM * sizeof(float), stream);
        // GEMM with fused BN-stats epilogue
        gemm_mfma_k<true, false, true, true><<<gemmN, b256, 0, stream>>>(
            gh, gl, Wrf, xh, xl, Wtf, degf, br, bufa, bnsums, N, K);
        bn_finalize_k<<<1, dim3(192), 0, stream>>>(bnsums, gamma + l * HDIM,
                                                   beta + l * HDIM, bnss, 1.0f / N);
        bn_apply_split_k<<<(N * 24 + 255) / 256, b256, 0, stream>>>(bufa, bnss, xh, xl, N);
    }

    // ---- pool
    pool_k<<<G, dim3(192), 0, stream>>>(xh, xl, start, gsum, G);

    // ---- head MLP (MFMA path)
    split_k<<<((G * HDIM / 8) + 255) / 256, b256, 0, stream>>>(gsum, gsh, gsl, G * HDIM / 8);
    gemm_mfma_k<false, true, false, false><<<gemmG, b256, 0, stream>>>(
        gsh, gsl, Wh1f, nullptr, nullptr, nullptr, nullptr, bh1, g1, nullptr, G, HDIM);
    split_k<<<((G * HDIM / 8) + 255) / 256, b256, 0, stream>>>(g1, g1h, g1l, G * HDIM / 8);
    gemm_mfma_k<false, false, false, false><<<gemmG, b256, 0, stream>>>(
        g1h, g1l, Wh2f, nullptr, nullptr, nullptr, nullptr, bh2, g2, nullptr, G, HDIM);
    out_dot_k<<<G, dim3(64), 0, stream>>>(g2, Wout, bout, out, G);
}

// Round 6
// 924.546 us; speedup vs baseline: 1.2027x; 1.2027x over previous
//
#include <hip/hip_runtime.h>

#define HDIM 192
#define EPS 1e-5f

typedef __attribute__((ext_vector_type(8))) short short8;
typedef __attribute__((ext_vector_type(4))) float floatx4;

__device__ __forceinline__ float bf2f(ushort h) {
    union { uint u; float f; } c; c.u = ((uint)h) << 16; return c.f;
}
__device__ __forceinline__ ushort f2bf(float x) {
    union { float f; uint u; } c; c.f = x; return (ushort)(c.u >> 16);
}
// split fp32 into bf16 hi + bf16 lo (truncation; residual ~2^-16 relative)
__device__ __forceinline__ void splitf(float x, ushort& hi, ushort& lo) {
    hi = f2bf(x);
    lo = f2bf(x - bf2f(hi));
}

// ---------------------------------------------------------------------------
// Weight prep: W[K,192] fp32 (nmat stacked) -> frag-ordered split planes.
// Per k-chunk (32 k): [plane(hi,lo)][ct(12)][lane(64)][j(8)] = 12288 ushorts.
// ---------------------------------------------------------------------------
__global__ __launch_bounds__(256) void prep_w_k(
    const float* __restrict__ W, ushort* __restrict__ Wf, int K, int nmat)
{
    int perMat = (K >> 5) * 12 * 64;
    int idx = blockIdx.x * 256 + threadIdx.x;
    if (idx >= perMat * nmat) return;
    int mat = idx / perMat;
    int r = idx - mat * perMat;
    int lane = r & 63;
    int ct = (r >> 6) % 12;
    int kc = r / (12 * 64);
    int col = ct * 16 + (lane & 15);
    int kb  = kc * 32 + (lane >> 4) * 8;
    const float* Wm = W + (size_t)mat * K * HDIM;
    ushort* base = Wf + (size_t)mat * K * HDIM * 2;
    size_t o = (size_t)kc * 12288 + (size_t)(ct * 64 + lane) * 8;
    #pragma unroll
    for (int j = 0; j < 8; ++j) {
        ushort hi, lo;
        splitf(Wm[(size_t)(kb + j) * HDIM + col], hi, lo);
        base[o + j]        = hi;
        base[o + 6144 + j] = lo;
    }
}

// ---------------------------------------------------------------------------
// split fp32 array -> bf16 hi/lo planes (8 elements per thread)
// ---------------------------------------------------------------------------
__global__ __launch_bounds__(256) void split_k(
    const float* __restrict__ src, ushort* __restrict__ hi,
    ushort* __restrict__ lo, int n8)
{
    int idx = blockIdx.x * 256 + threadIdx.x;
    if (idx >= n8) return;
    float4 v0 = ((const float4*)src)[idx * 2];
    float4 v1 = ((const float4*)src)[idx * 2 + 1];
    float v[8] = {v0.x, v0.y, v0.z, v0.w, v1.x, v1.y, v1.z, v1.w};
    ushort h[8], l[8];
    #pragma unroll
    for (int t = 0; t < 8; ++t) splitf(v[t], h[t], l[t]);
    uint4 ph, pl;
    ph.x = h[0] | ((uint)h[1] << 16); ph.y = h[2] | ((uint)h[3] << 16);
    ph.z = h[4] | ((uint)h[5] << 16); ph.w = h[6] | ((uint)h[7] << 16);
    pl.x = l[0] | ((uint)l[1] << 16); pl.y = l[2] | ((uint)l[3] << 16);
    pl.z = l[4] | ((uint)l[5] << 16); pl.w = l[6] | ((uint)l[7] << 16);
    *(uint4*)(hi + (size_t)idx * 8) = ph;
    *(uint4*)(lo + (size_t)idx * 8) = pl;
}

// ---------------------------------------------------------------------------
// MFMA GEMM: C[N,192] = A1@W1 (+ A2@W2) + bias-term, optional fused BN stats.
// Block: 256 thr / 4 waves, tile 128 rows x 192 cols.
// NO LDS staging, NO K-loop barriers: B fragments are loaded directly from
// global (frag-major layout, perfectly coalesced, L2-resident weights).
// Per chunk: 20 independent b128 loads in flight, then 72 MFMAs.
// 3-term split product: Ah*Bh + Al*Bh + Ah*Bl.
// ---------------------------------------------------------------------------
template<bool DUAL, bool RELU, bool DEG, bool STATS>
__global__ __launch_bounds__(256) void gemm_mfma_k(
    const ushort* __restrict__ A1h, const ushort* __restrict__ A1l,
    const ushort* __restrict__ W1f,
    const ushort* __restrict__ A2h, const ushort* __restrict__ A2l,
    const ushort* __restrict__ W2f,
    const float* __restrict__ degf, const float* __restrict__ bias,
    float* __restrict__ C, float* __restrict__ stats, int N, int K)
{
    __shared__ float sstat[2][HDIM];
    const int tid  = threadIdx.x;
    const int wave = tid >> 6;
    const int lane = tid & 63;
    const int r2 = wave & 1;
    const int c2 = wave >> 1;
    const int row0 = blockIdx.x * 128 + r2 * 64;
    const int m16 = lane & 15;
    const int g4  = lane >> 4;

    if (STATS && tid < HDIM) { sstat[0][tid] = 0.f; sstat[1][tid] = 0.f; }

    // clamped row offsets (in elements) for this lane's 4 row-fragments
    int rowoff[4];
    #pragma unroll
    for (int s = 0; s < 4; ++s) {
        int rr = row0 + s * 16 + m16; if (rr >= N) rr = N - 1;
        rowoff[s] = rr * K;
    }

    floatx4 acc[4][6];
    #pragma unroll
    for (int s = 0; s < 4; ++s)
        #pragma unroll
        for (int ct = 0; ct < 6; ++ct) acc[s][ct] = (floatx4){0.f, 0.f, 0.f, 0.f};

    const int nkc = K >> 5;
    const int nphase = DUAL ? 2 : 1;
    for (int phase = 0; phase < nphase; ++phase) {
        const ushort* Ah = phase ? A2h : A1h;
        const ushort* Al = phase ? A2l : A1l;
        const ushort* Wf = phase ? W2f : W1f;
        for (int kc = 0; kc < nkc; ++kc) {
            // B fragments straight from global (frag-major, coalesced, L2-hot)
            const ushort* Wb = Wf + (size_t)kc * 12288 + (size_t)(c2 * 6 * 64 + lane) * 8;
            short8 bh[6], bl[6];
            #pragma unroll
            for (int ct = 0; ct < 6; ++ct) {
                bh[ct] = *(const short8*)(Wb + ct * 512);
                bl[ct] = *(const short8*)(Wb + 6144 + ct * 512);
            }
            // A fragments (b128, row-major planes)
            const int co = kc * 32 + g4 * 8;
            short8 ah[4], al[4];
            #pragma unroll
            for (int s = 0; s < 4; ++s) {
                ah[s] = *(const short8*)(Ah + rowoff[s] + co);
                al[s] = *(const short8*)(Al + rowoff[s] + co);
            }
            #pragma unroll
            for (int ct = 0; ct < 6; ++ct) {
                #pragma unroll
                for (int s = 0; s < 4; ++s) {
                    acc[s][ct] = __builtin_amdgcn_mfma_f32_16x16x32_bf16(ah[s], bh[ct], acc[s][ct], 0, 0, 0);
                    acc[s][ct] = __builtin_amdgcn_mfma_f32_16x16x32_bf16(al[s], bh[ct], acc[s][ct], 0, 0, 0);
                    acc[s][ct] = __builtin_amdgcn_mfma_f32_16x16x32_bf16(ah[s], bl[ct], acc[s][ct], 0, 0, 0);
                }
            }
        }
    }

    // make sstat zero-init visible before epilogue atomics (only barrier here)
    if (STATS) __syncthreads();

    // epilogue: C/D layout col=lane&15, row=(lane>>4)*4+reg  [m89]
    #pragma unroll
    for (int ct = 0; ct < 6; ++ct) {
        int col = c2 * 96 + ct * 16 + m16;
        float bv = bias ? bias[col] : 0.f;
        float lsum = 0.f, lsq = 0.f;
        #pragma unroll
        for (int s = 0; s < 4; ++s) {
            #pragma unroll
            for (int reg = 0; reg < 4; ++reg) {
                int rr = row0 + s * 16 + g4 * 4 + reg;
                if (rr < N) {
                    float v = acc[s][ct][reg] + (DEG ? degf[rr] * bv : bv);
                    if (STATS) { lsum += v; lsq += v * v; }
                    if (RELU) v = fmaxf(v, 0.f);
                    C[(size_t)rr * HDIM + col] = v;
                }
            }
        }
        if (STATS) {
            lsum += __shfl_xor(lsum, 16); lsum += __shfl_xor(lsum, 32);
            lsq  += __shfl_xor(lsq, 16);  lsq  += __shfl_xor(lsq, 32);
            if (g4 == 0) {
                atomicAdd(&sstat[0][col], lsum);
                atomicAdd(&sstat[1][col], lsq);
            }
        }
    }
    if (STATS) {
        __syncthreads();
        if (tid < HDIM) {
            atomicAdd(&stats[tid], sstat[0][tid]);
            atomicAdd(&stats[HDIM + tid], sstat[1][tid]);
        }
    }
}

// ---------------------------------------------------------------------------
// CSR construction from edge_dst
// ---------------------------------------------------------------------------
__global__ __launch_bounds__(256) void hist_k(
    const int* __restrict__ dst, int* __restrict__ deg, int E)
{
    int e = blockIdx.x * 256 + threadIdx.x;
    if (e < E) atomicAdd(&deg[dst[e]], 1);
}

__global__ __launch_bounds__(256) void block_sum_k(
    const int* __restrict__ deg, int* __restrict__ bsum, int N)
{
    __shared__ int s[256];
    int t = threadIdx.x;
    int n = blockIdx.x * 256 + t;
    s[t] = (n < N) ? deg[n] : 0;
    __syncthreads();
    for (int off = 128; off > 0; off >>= 1) {
        if (t < off) s[t] += s[t + off];
        __syncthreads();
    }
    if (t == 0) bsum[blockIdx.x] = s[0];
}

__global__ __launch_bounds__(512) void scan_bsum_k(int* __restrict__ bsum, int nb)
{
    __shared__ int s[512];
    int t = threadIdx.x;
    int v = (t < nb) ? bsum[t] : 0;
    s[t] = v;
    __syncthreads();
    for (int off = 1; off < 512; off <<= 1) {
        int u = (t >= off) ? s[t - off] : 0;
        __syncthreads();
        s[t] += u;
        __syncthreads();
    }
    if (t < nb) bsum[t] = s[t] - v;   // exclusive
}

__global__ __launch_bounds__(256) void row_ptr_k(
    const int* __restrict__ deg, const int* __restrict__ bsum,
    int* __restrict__ row_ptr, int* __restrict__ cursor,
    float* __restrict__ degf, int N, int E)
{
    __shared__ int s[256];
    int t = threadIdx.x;
    int n = blockIdx.x * 256 + t;
    int v = (n < N) ? deg[n] : 0;
    s[t] = v;
    __syncthreads();
    for (int off = 1; off < 256; off <<= 1) {
        int u = (t >= off) ? s[t - off] : 0;
        __syncthreads();
        s[t] += u;
        __syncthreads();
    }
    int ex = s[t] - v + bsum[blockIdx.x];
    if (n < N) {
        row_ptr[n] = ex;
        cursor[n]  = ex;
        degf[n]    = (float)v;
    }
    if (blockIdx.x == 0 && t == 0) row_ptr[N] = E;
}

__global__ __launch_bounds__(256) void fill_k(
    const int* __restrict__ src, const int* __restrict__ dst,
    int* __restrict__ cursor, int* __restrict__ col, int E)
{
    int e = blockIdx.x * 256 + threadIdx.x;
    if (e < E) {
        int p = atomicAdd(&cursor[dst[e]], 1);
        col[p] = src[e];
    }
}

// ---------------------------------------------------------------------------
// gather on split planes: g[n] = sum_{j} (hi+lo)[col[j]]; output re-split.
// ---------------------------------------------------------------------------
__global__ __launch_bounds__(256) void gather_split_k(
    const ushort* __restrict__ xh, const ushort* __restrict__ xl,
    const int* __restrict__ row_ptr, const int* __restrict__ col,
    ushort* __restrict__ gh, ushort* __restrict__ gl, int N, int K)
{
    int WQ = K >> 3;
    int idx = blockIdx.x * 256 + threadIdx.x;
    if (idx >= N * WQ) return;
    int n = idx / WQ;
    int q = (idx - n * WQ) * 8;
    int j0 = row_ptr[n], j1 = row_ptr[n + 1];
    float acc[8] = {0.f,0.f,0.f,0.f,0.f,0.f,0.f,0.f};
    for (int j = j0; j < j1; ++j) {
        int s = col[j];
        uint4 hv = *(const uint4*)(xh + (size_t)s * K + q);
        uint4 lv = *(const uint4*)(xl + (size_t)s * K + q);
        uint hu[4] = {hv.x, hv.y, hv.z, hv.w};
        uint lu[4] = {lv.x, lv.y, lv.z, lv.w};
        #pragma unroll
        for (int t = 0; t < 4; ++t) {
            acc[2*t]   += bf2f((ushort)(hu[t] & 0xffffu)) + bf2f((ushort)(lu[t] & 0xffffu));
            acc[2*t+1] += bf2f((ushort)(hu[t] >> 16))     + bf2f((ushort)(lu[t] >> 16));
        }
    }
    ushort oh[8], ol[8];
    #pragma unroll
    for (int t = 0; t < 8; ++t) splitf(acc[t], oh[t], ol[t]);
    uint4 ph, pl;
    ph.x = oh[0] | ((uint)oh[1] << 16); ph.y = oh[2] | ((uint)oh[3] << 16);
    ph.z = oh[4] | ((uint)oh[5] << 16); ph.w = oh[6] | ((uint)oh[7] << 16);
    pl.x = ol[0] | ((uint)ol[1] << 16); pl.y = ol[2] | ((uint)ol[3] << 16);
    pl.z = ol[4] | ((uint)ol[5] << 16); pl.w = ol[6] | ((uint)ol[7] << 16);
    *(uint4*)(gh + (size_t)n * K + q) = ph;
    *(uint4*)(gl + (size_t)n * K + q) = pl;
}

// ---------------------------------------------------------------------------
// batchnorm finalize + apply
// ---------------------------------------------------------------------------
__global__ void bn_finalize_k(const float* __restrict__ sums,
                              const float* __restrict__ gamma,
                              const float* __restrict__ beta,
                              float* __restrict__ ss, float invN)
{
    int c = threadIdx.x;
    float mu  = sums[c] * invN;
    float var = sums[HDIM + c] * invN - mu * mu;
    float sc  = gamma[c] * rsqrtf(var + EPS);
    ss[c]        = sc;
    ss[HDIM + c] = beta[c] - mu * sc;
}

__global__ __launch_bounds__(256) void bn_apply_split_k(
    const float* __restrict__ h, const float* __restrict__ ss,
    ushort* __restrict__ xh, ushort* __restrict__ xl, int N)
{
    int idx = blockIdx.x * 256 + threadIdx.x;   // over N*24
    if (idx >= N * 24) return;
    int q = (idx % 24) * 8;
    float4 v0 = ((const float4*)h)[idx * 2];
    float4 v1 = ((const float4*)h)[idx * 2 + 1];
    float v[8] = {v0.x, v0.y, v0.z, v0.w, v1.x, v1.y, v1.z, v1.w};
    ushort oh[8], ol[8];
    #pragma unroll
    for (int t = 0; t < 8; ++t) {
        float r = fmaxf(v[t] * ss[q + t] + ss[HDIM + q + t], 0.f);
        splitf(r, oh[t], ol[t]);
    }
    uint4 ph, pl;
    ph.x = oh[0] | ((uint)oh[1] << 16); ph.y = oh[2] | ((uint)oh[3] << 16);
    ph.z = oh[4] | ((uint)oh[5] << 16); ph.w = oh[6] | ((uint)oh[7] << 16);
    pl.x = ol[0] | ((uint)ol[1] << 16); pl.y = ol[2] | ((uint)ol[3] << 16);
    pl.z = ol[4] | ((uint)ol[5] << 16); pl.w = ol[6] | ((uint)ol[7] << 16);
    *(uint4*)(xh + (size_t)idx * 8) = ph;
    *(uint4*)(xl + (size_t)idx * 8) = pl;
}

// ---------------------------------------------------------------------------
// pool over contiguous per-graph row ranges (batch sorted)
// ---------------------------------------------------------------------------
__global__ __launch_bounds__(256) void init_start_k(int* __restrict__ start, int G, int N)
{
    int g = blockIdx.x * 256 + threadIdx.x;
    if (g <= G) start[g] = N;
}

__global__ __launch_bounds__(256) void bound_k(
    const int* __restrict__ batch, int* __restrict__ start, int N)
{
    int n = blockIdx.x * 256 + threadIdx.x;
    if (n >= N) return;
    int b  = batch[n];
    int bp = (n == 0) ? -1 : batch[n - 1];
    for (int g = bp + 1; g <= b; ++g) start[g] = n;
}

__global__ __launch_bounds__(192) void pool_k(
    const ushort* __restrict__ xh, const ushort* __restrict__ xl,
    const int* __restrict__ start, float* __restrict__ gout, int G)
{
    int g = blockIdx.x;
    int c = threadIdx.x;
    int r0 = start[g], r1 = start[g + 1];
    float s = 0.f;
    for (int r = r0; r < r1; ++r) {
        size_t o = (size_t)r * HDIM + c;
        s += bf2f(xh[o]) + bf2f(xl[o]);
    }
    float cnt = (float)(r1 - r0);
    gout[(size_t)g * HDIM + c] = s / fmaxf(cnt, 1.f);
}

// ---------------------------------------------------------------------------
__global__ __launch_bounds__(64) void out_dot_k(
    const float* __restrict__ g2, const float* __restrict__ Wout,
    const float* __restrict__ bout, float* __restrict__ out, int G)
{
    int gi = blockIdx.x;
    int t = threadIdx.x;
    const float* r = g2 + (size_t)gi * HDIM;
    float s = r[t] * Wout[t] + r[t + 64] * Wout[t + 64] + r[t + 128] * Wout[t + 128];
    #pragma unroll
    for (int off = 32; off > 0; off >>= 1) s += __shfl_down(s, off, 64);
    if (t == 0) out[gi] = s + bout[0];
}

// ---------------------------------------------------------------------------
extern "C" void kernel_launch(void* const* d_in, const int* in_sizes, int n_in,
                              void* d_out, int out_size, void* d_ws, size_t ws_size,
                              hipStream_t stream)
{
    const float* x      = (const float*)d_in[0];
    const int*   esrc   = (const int*)d_in[1];
    const int*   edst   = (const int*)d_in[2];
    const int*   batch  = (const int*)d_in[3];
    const float* Wrel0  = (const float*)d_in[4];
    const float* brel0  = (const float*)d_in[5];
    const float* Wroot0 = (const float*)d_in[6];
    const float* Wrel   = (const float*)d_in[7];
    const float* brel   = (const float*)d_in[8];
    const float* Wroot  = (const float*)d_in[9];
    const float* gamma  = (const float*)d_in[10];
    const float* beta   = (const float*)d_in[11];
    const float* Wh1    = (const float*)d_in[12];
    const float* bh1    = (const float*)d_in[13];
    const float* Wh2    = (const float*)d_in[14];
    const float* bh2    = (const float*)d_in[15];
    const float* Wout   = (const float*)d_in[16];
    const float* bout   = (const float*)d_in[17];
    float* out = (float*)d_out;

    const int N  = in_sizes[3];           // 100000
    const int E  = in_sizes[1];           // 400000
    const int K0 = in_sizes[0] / N;       // 32
    const int G  = out_size;              // 2000
    const int nBlocks = (N + 255) / 256;

    char* p = (char*)d_ws;
    auto carve = [&](size_t bytes) -> void* {
        void* r = (void*)p; p += (bytes + 255) & ~(size_t)255; return r;
    };
    float*  bufa  = (float*) carve((size_t)N * HDIM * 4);
    ushort* xh    = (ushort*)carve((size_t)N * HDIM * 2);
    ushort* xl    = (ushort*)carve((size_t)N * HDIM * 2);
    ushort* gh    = (ushort*)carve((size_t)N * HDIM * 2);
    ushort* gl    = (ushort*)carve((size_t)N * HDIM * 2);
    float*  gsum  = (float*) carve((size_t)G * HDIM * 4);
    float*  g1    = (float*) carve((size_t)G * HDIM * 4);
    float*  g2    = (float*) carve((size_t)G * HDIM * 4);
    ushort* gsh   = (ushort*)carve((size_t)G * HDIM * 2);
    ushort* gsl   = (ushort*)carve((size_t)G * HDIM * 2);
    ushort* g1h   = (ushort*)carve((size_t)G * HDIM * 2);
    ushort* g1l   = (ushort*)carve((size_t)G * HDIM * 2);
    float*  bnsums= (float*) carve(2 * HDIM * 4);
    float*  bnss  = (float*) carve(2 * HDIM * 4);
    float*  degf  = (float*) carve((size_t)N * 4);
    int*    deg   = (int*)   carve((size_t)N * 4);
    int*    row_ptr=(int*)   carve((size_t)(N + 1) * 4);
    int*    cursor= (int*)   carve((size_t)N * 4);
    int*    col   = (int*)   carve((size_t)E * 4);
    int*    bsum  = (int*)   carve((size_t)nBlocks * 4);
    int*    start = (int*)   carve((size_t)(G + 1) * 4);
    ushort* Wrel0f= (ushort*)carve((size_t)K0 * HDIM * 2 * 2);
    ushort* Wroot0f=(ushort*)carve((size_t)K0 * HDIM * 2 * 2);
    ushort* Wrelf = (ushort*)carve((size_t)3 * HDIM * HDIM * 2 * 2);
    ushort* Wrootf= (ushort*)carve((size_t)3 * HDIM * HDIM * 2 * 2);
    ushort* Wh1f  = (ushort*)carve((size_t)HDIM * HDIM * 2 * 2);
    ushort* Wh2f  = (ushort*)carve((size_t)HDIM * HDIM * 2 * 2);

    dim3 b256(256);
    const int eBlocks = (E + 255) / 256;
    const int gemmN = (N + 127) / 128;
    const int gemmG = (G + 127) / 128;

    // ---- weight prep (frag-ordered hi/lo split)
    {
        int t0 = (K0 >> 5) * 12 * 64;
        int t1 = (HDIM >> 5) * 12 * 64;
        prep_w_k<<<(t0 + 255) / 256, b256, 0, stream>>>(Wrel0,  Wrel0f,  K0, 1);
        prep_w_k<<<(t0 + 255) / 256, b256, 0, stream>>>(Wroot0, Wroot0f, K0, 1);
        prep_w_k<<<(3 * t1 + 255) / 256, b256, 0, stream>>>(Wrel,  Wrelf,  HDIM, 3);
        prep_w_k<<<(3 * t1 + 255) / 256, b256, 0, stream>>>(Wroot, Wrootf, HDIM, 3);
        prep_w_k<<<(t1 + 255) / 256, b256, 0, stream>>>(Wh1, Wh1f, HDIM, 1);
        prep_w_k<<<(t1 + 255) / 256, b256, 0, stream>>>(Wh2, Wh2f, HDIM, 1);
    }
    split_k<<<((N * K0 / 8) + 255) / 256, b256, 0, stream>>>(x, xh, xl, N * K0 / 8);

    // ---- CSR build
    hipMemsetAsync(deg, 0, N * sizeof(int), stream);
    hist_k<<<eBlocks, b256, 0, stream>>>(edst, deg, E);
    block_sum_k<<<nBlocks, b256, 0, stream>>>(deg, bsum, N);
    scan_bsum_k<<<1, dim3(512), 0, stream>>>(bsum, nBlocks);
    row_ptr_k<<<nBlocks, b256, 0, stream>>>(deg, bsum, row_ptr, cursor, degf, N, E);
    fill_k<<<eBlocks, b256, 0, stream>>>(esrc, edst, cursor, col, E);

    // ---- graph boundaries for pooling
    init_start_k<<<(G + 256) / 256, b256, 0, stream>>>(start, G, N);
    bound_k<<<nBlocks, b256, 0, stream>>>(batch, start, N);

    // ---- layers
    for (int l = 0; l < 4; ++l) {
        const int K = (l == 0) ? K0 : HDIM;
        const ushort* Wrf = (l == 0) ? Wrel0f  : Wrelf  + (size_t)(l - 1) * HDIM * HDIM * 2;
        const ushort* Wtf = (l == 0) ? Wroot0f : Wrootf + (size_t)(l - 1) * HDIM * HDIM * 2;
        const float*  br  = (l == 0) ? brel0   : brel   + (size_t)(l - 1) * HDIM;

        int gthreads = N * (K >> 3);
        gather_split_k<<<(gthreads + 255) / 256, b256, 0, stream>>>(
            xh, xl, row_ptr, col, gh, gl, N, K);
        hipMemsetAsync(bnsums, 0, 2 * HDIM * sizeof(float), stream);
        // GEMM with fused BN-stats epilogue
        gemm_mfma_k<true, false, true, true><<<gemmN, b256, 0, stream>>>(
            gh, gl, Wrf, xh, xl, Wtf, degf, br, bufa, bnsums, N, K);
        bn_finalize_k<<<1, dim3(192), 0, stream>>>(bnsums, gamma + l * HDIM,
                                                   beta + l * HDIM, bnss, 1.0f / N);
        bn_apply_split_k<<<(N * 24 + 255) / 256, b256, 0, stream>>>(bufa, bnss, xh, xl, N);
    }

    // ---- pool
    pool_k<<<G, dim3(192), 0, stream>>>(xh, xl, start, gsum, G);

    // ---- head MLP (MFMA path)
    split_k<<<((G * HDIM / 8) + 255) / 256, b256, 0, stream>>>(gsum, gsh, gsl, G * HDIM / 8);
    gemm_mfma_k<false, true, false, false><<<gemmG, b256, 0, stream>>>(
        gsh, gsl, Wh1f, nullptr, nullptr, nullptr, nullptr, bh1, g1, nullptr, G, HDIM);
    split_k<<<((G * HDIM / 8) + 255) / 256, b256, 0, stream>>>(g1, g1h, g1l, G * HDIM / 8);
    gemm_mfma_k<false, false, false, false><<<gemmG, b256, 0, stream>>>(
        g1h, g1l, Wh2f, nullptr, nullptr, nullptr, nullptr, bh2, g2, nullptr, G, HDIM);
    out_dot_k<<<G, dim3(64), 0, stream>>>(g2, Wout, bout, out, G);
}

// Round 7
// 785.653 us; speedup vs baseline: 1.4153x; 1.1768x over previous
//
#include <hip/hip_runtime.h>

#define HDIM 192
#define EPS 1e-5f

typedef __attribute__((ext_vector_type(8))) _Float16 half8;
typedef __attribute__((ext_vector_type(4))) float floatx4;

__device__ __forceinline__ float h2f(ushort u) {
    union { ushort u; _Float16 h; } c; c.u = u; return (float)c.h;
}
__device__ __forceinline__ ushort f2h(float x) {
    _Float16 h = (_Float16)x;           // RTN
    union { _Float16 h; ushort u; } c; c.h = h; return c.u;
}
// split fp32 into fp16 hi + fp16 lo (RTN; combined rel err ~2^-22)
__device__ __forceinline__ void splitf(float x, ushort& hi, ushort& lo) {
    hi = f2h(x);
    lo = f2h(x - h2f(hi));
}

// ---------------------------------------------------------------------------
// Weight prep: W[K,192] fp32 (nmat stacked) -> frag-ordered fp16 hi/lo planes.
// Per k-chunk (32 k): [plane(hi,lo)][ct(12)][lane(64)][j(8)] = 12288 ushorts.
// B-frag layout of mfma_f32_16x16x32_f16: n=lane&15, k=(lane>>4)*8+j.
// ---------------------------------------------------------------------------
__global__ __launch_bounds__(256) void prep_w_k(
    const float* __restrict__ W, ushort* __restrict__ Wf, int K, int nmat)
{
    int perMat = (K >> 5) * 12 * 64;
    int idx = blockIdx.x * 256 + threadIdx.x;
    if (idx >= perMat * nmat) return;
    int mat = idx / perMat;
    int r = idx - mat * perMat;
    int lane = r & 63;
    int ct = (r >> 6) % 12;
    int kc = r / (12 * 64);
    int col = ct * 16 + (lane & 15);
    int kb  = kc * 32 + (lane >> 4) * 8;
    const float* Wm = W + (size_t)mat * K * HDIM;
    ushort* base = Wf + (size_t)mat * K * HDIM * 2;
    size_t o = (size_t)kc * 12288 + (size_t)(ct * 64 + lane) * 8;
    #pragma unroll
    for (int j = 0; j < 8; ++j) {
        ushort hi, lo;
        splitf(Wm[(size_t)(kb + j) * HDIM + col], hi, lo);
        base[o + j]        = hi;
        base[o + 6144 + j] = lo;
    }
}

// ---------------------------------------------------------------------------
// convert fp32 array -> single fp16 plane (8 elements per thread, RTN)
// ---------------------------------------------------------------------------
__global__ __launch_bounds__(256) void conv_h_k(
    const float* __restrict__ src, ushort* __restrict__ dst, int n8)
{
    int idx = blockIdx.x * 256 + threadIdx.x;
    if (idx >= n8) return;
    float4 v0 = ((const float4*)src)[idx * 2];
    float4 v1 = ((const float4*)src)[idx * 2 + 1];
    float v[8] = {v0.x, v0.y, v0.z, v0.w, v1.x, v1.y, v1.z, v1.w};
    ushort h[8];
    #pragma unroll
    for (int t = 0; t < 8; ++t) h[t] = f2h(v[t]);
    uint4 ph;
    ph.x = h[0] | ((uint)h[1] << 16); ph.y = h[2] | ((uint)h[3] << 16);
    ph.z = h[4] | ((uint)h[5] << 16); ph.w = h[6] | ((uint)h[7] << 16);
    *(uint4*)(dst + (size_t)idx * 8) = ph;
}

// ---------------------------------------------------------------------------
// MFMA GEMM: C[N,192] = A1@W1 (+ A2@W2) + bias-term, optional fused BN stats.
// Block: 256 thr / 4 waves, tile 128 rows x 192 cols. No LDS staging, no
// K-loop barriers (frag-major B direct from global, L2-hot).
// fp16 2-term: A single plane (RTN), W split hi/lo: Ah*Bh + Ah*Bl.
// ---------------------------------------------------------------------------
template<bool DUAL, bool RELU, bool DEG, bool STATS>
__global__ __launch_bounds__(256) void gemm_mfma_k(
    const ushort* __restrict__ A1h, const ushort* __restrict__ W1f,
    const ushort* __restrict__ A2h, const ushort* __restrict__ W2f,
    const float* __restrict__ degf, const float* __restrict__ bias,
    float* __restrict__ C, float* __restrict__ stats, int N, int K)
{
    __shared__ float sstat[2][HDIM];
    const int tid  = threadIdx.x;
    const int wave = tid >> 6;
    const int lane = tid & 63;
    const int r2 = wave & 1;
    const int c2 = wave >> 1;
    const int row0 = blockIdx.x * 128 + r2 * 64;
    const int m16 = lane & 15;
    const int g4  = lane >> 4;

    if (STATS && tid < HDIM) { sstat[0][tid] = 0.f; sstat[1][tid] = 0.f; }

    int rowoff[4];
    #pragma unroll
    for (int s = 0; s < 4; ++s) {
        int rr = row0 + s * 16 + m16; if (rr >= N) rr = N - 1;
        rowoff[s] = rr * K;
    }

    floatx4 acc[4][6];
    #pragma unroll
    for (int s = 0; s < 4; ++s)
        #pragma unroll
        for (int ct = 0; ct < 6; ++ct) acc[s][ct] = (floatx4){0.f, 0.f, 0.f, 0.f};

    const int nkc = K >> 5;
    const int nphase = DUAL ? 2 : 1;
    for (int phase = 0; phase < nphase; ++phase) {
        const ushort* Ah = phase ? A2h : A1h;
        const ushort* Wf = phase ? W2f : W1f;
        for (int kc = 0; kc < nkc; ++kc) {
            const ushort* Wb = Wf + (size_t)kc * 12288 + (size_t)(c2 * 6 * 64 + lane) * 8;
            half8 bh[6], bl[6];
            #pragma unroll
            for (int ct = 0; ct < 6; ++ct) {
                bh[ct] = *(const half8*)(Wb + ct * 512);
                bl[ct] = *(const half8*)(Wb + 6144 + ct * 512);
            }
            const int co = kc * 32 + g4 * 8;
            half8 ah[4];
            #pragma unroll
            for (int s = 0; s < 4; ++s)
                ah[s] = *(const half8*)(Ah + rowoff[s] + co);
            #pragma unroll
            for (int ct = 0; ct < 6; ++ct) {
                #pragma unroll
                for (int s = 0; s < 4; ++s) {
                    acc[s][ct] = __builtin_amdgcn_mfma_f32_16x16x32_f16(ah[s], bh[ct], acc[s][ct], 0, 0, 0);
                    acc[s][ct] = __builtin_amdgcn_mfma_f32_16x16x32_f16(ah[s], bl[ct], acc[s][ct], 0, 0, 0);
                }
            }
        }
    }

    if (STATS) __syncthreads();   // sstat zero-init visible

    // epilogue: C/D layout col=lane&15, row=(lane>>4)*4+reg  [m89]
    #pragma unroll
    for (int ct = 0; ct < 6; ++ct) {
        int col = c2 * 96 + ct * 16 + m16;
        float bv = bias ? bias[col] : 0.f;
        float lsum = 0.f, lsq = 0.f;
        #pragma unroll
        for (int s = 0; s < 4; ++s) {
            #pragma unroll
            for (int reg = 0; reg < 4; ++reg) {
                int rr = row0 + s * 16 + g4 * 4 + reg;
                if (rr < N) {
                    float v = acc[s][ct][reg] + (DEG ? degf[rr] * bv : bv);
                    if (STATS) { lsum += v; lsq += v * v; }
                    if (RELU) v = fmaxf(v, 0.f);
                    C[(size_t)rr * HDIM + col] = v;
                }
            }
        }
        if (STATS) {
            lsum += __shfl_xor(lsum, 16); lsum += __shfl_xor(lsum, 32);
            lsq  += __shfl_xor(lsq, 16);  lsq  += __shfl_xor(lsq, 32);
            if (g4 == 0) {
                atomicAdd(&sstat[0][col], lsum);
                atomicAdd(&sstat[1][col], lsq);
            }
        }
    }
    if (STATS) {
        __syncthreads();
        if (tid < HDIM) {
            atomicAdd(&stats[tid], sstat[0][tid]);
            atomicAdd(&stats[HDIM + tid], sstat[1][tid]);
        }
    }
}

// ---------------------------------------------------------------------------
// CSR construction from edge_dst
// ---------------------------------------------------------------------------
__global__ __launch_bounds__(256) void hist_k(
    const int* __restrict__ dst, int* __restrict__ deg, int E)
{
    int e = blockIdx.x * 256 + threadIdx.x;
    if (e < E) atomicAdd(&deg[dst[e]], 1);
}

__global__ __launch_bounds__(256) void block_sum_k(
    const int* __restrict__ deg, int* __restrict__ bsum, int N)
{
    __shared__ int s[256];
    int t = threadIdx.x;
    int n = blockIdx.x * 256 + t;
    s[t] = (n < N) ? deg[n] : 0;
    __syncthreads();
    for (int off = 128; off > 0; off >>= 1) {
        if (t < off) s[t] += s[t + off];
        __syncthreads();
    }
    if (t == 0) bsum[blockIdx.x] = s[0];
}

__global__ __launch_bounds__(512) void scan_bsum_k(int* __restrict__ bsum, int nb)
{
    __shared__ int s[512];
    int t = threadIdx.x;
    int v = (t < nb) ? bsum[t] : 0;
    s[t] = v;
    __syncthreads();
    for (int off = 1; off < 512; off <<= 1) {
        int u = (t >= off) ? s[t - off] : 0;
        __syncthreads();
        s[t] += u;
        __syncthreads();
    }
    if (t < nb) bsum[t] = s[t] - v;   // exclusive
}

__global__ __launch_bounds__(256) void row_ptr_k(
    const int* __restrict__ deg, const int* __restrict__ bsum,
    int* __restrict__ row_ptr, int* __restrict__ cursor,
    float* __restrict__ degf, int N, int E)
{
    __shared__ int s[256];
    int t = threadIdx.x;
    int n = blockIdx.x * 256 + t;
    int v = (n < N) ? deg[n] : 0;
    s[t] = v;
    __syncthreads();
    for (int off = 1; off < 256; off <<= 1) {
        int u = (t >= off) ? s[t - off] : 0;
        __syncthreads();
        s[t] += u;
        __syncthreads();
    }
    int ex = s[t] - v + bsum[blockIdx.x];
    if (n < N) {
        row_ptr[n] = ex;
        cursor[n]  = ex;
        degf[n]    = (float)v;
    }
    if (blockIdx.x == 0 && t == 0) row_ptr[N] = E;
}

__global__ __launch_bounds__(256) void fill_k(
    const int* __restrict__ src, const int* __restrict__ dst,
    int* __restrict__ cursor, int* __restrict__ col, int E)
{
    int e = blockIdx.x * 256 + threadIdx.x;
    if (e < E) {
        int p = atomicAdd(&cursor[dst[e]], 1);
        col[p] = src[e];
    }
}

// ---------------------------------------------------------------------------
// gather on fp16 plane: g[n] = sum_{j} x[col[j]]; fp32 accumulate, RTN out.
// ---------------------------------------------------------------------------
__global__ __launch_bounds__(256) void gather_h_k(
    const ushort* __restrict__ xh, const int* __restrict__ row_ptr,
    const int* __restrict__ col, ushort* __restrict__ gh, int N, int K)
{
    int WQ = K >> 3;
    int idx = blockIdx.x * 256 + threadIdx.x;
    if (idx >= N * WQ) return;
    int n = idx / WQ;
    int q = (idx - n * WQ) * 8;
    int j0 = row_ptr[n], j1 = row_ptr[n + 1];
    float acc[8] = {0.f,0.f,0.f,0.f,0.f,0.f,0.f,0.f};
    for (int j = j0; j < j1; ++j) {
        int s = col[j];
        uint4 hv = *(const uint4*)(xh + (size_t)s * K + q);
        uint hu[4] = {hv.x, hv.y, hv.z, hv.w};
        #pragma unroll
        for (int t = 0; t < 4; ++t) {
            acc[2*t]   += h2f((ushort)(hu[t] & 0xffffu));
            acc[2*t+1] += h2f((ushort)(hu[t] >> 16));
        }
    }
    ushort oh[8];
    #pragma unroll
    for (int t = 0; t < 8; ++t) oh[t] = f2h(acc[t]);
    uint4 ph;
    ph.x = oh[0] | ((uint)oh[1] << 16); ph.y = oh[2] | ((uint)oh[3] << 16);
    ph.z = oh[4] | ((uint)oh[5] << 16); ph.w = oh[6] | ((uint)oh[7] << 16);
    *(uint4*)(gh + (size_t)n * K + q) = ph;
}

// ---------------------------------------------------------------------------
// batchnorm finalize + apply (single fp16 plane out)
// ---------------------------------------------------------------------------
__global__ void bn_finalize_k(const float* __restrict__ sums,
                              const float* __restrict__ gamma,
                              const float* __restrict__ beta,
                              float* __restrict__ ss, float invN)
{
    int c = threadIdx.x;
    float mu  = sums[c] * invN;
    float var = sums[HDIM + c] * invN - mu * mu;
    float sc  = gamma[c] * rsqrtf(var + EPS);
    ss[c]        = sc;
    ss[HDIM + c] = beta[c] - mu * sc;
}

__global__ __launch_bounds__(256) void bn_apply_h_k(
    const float* __restrict__ h, const float* __restrict__ ss,
    ushort* __restrict__ xh, int N)
{
    int idx = blockIdx.x * 256 + threadIdx.x;   // over N*24
    if (idx >= N * 24) return;
    int q = (idx % 24) * 8;
    float4 v0 = ((const float4*)h)[idx * 2];
    float4 v1 = ((const float4*)h)[idx * 2 + 1];
    float v[8] = {v0.x, v0.y, v0.z, v0.w, v1.x, v1.y, v1.z, v1.w};
    ushort oh[8];
    #pragma unroll
    for (int t = 0; t < 8; ++t) {
        float r = fmaxf(v[t] * ss[q + t] + ss[HDIM + q + t], 0.f);
        oh[t] = f2h(r);
    }
    uint4 ph;
    ph.x = oh[0] | ((uint)oh[1] << 16); ph.y = oh[2] | ((uint)oh[3] << 16);
    ph.z = oh[4] | ((uint)oh[5] << 16); ph.w = oh[6] | ((uint)oh[7] << 16);
    *(uint4*)(xh + (size_t)idx * 8) = ph;
}

// ---------------------------------------------------------------------------
// pool over contiguous per-graph row ranges (batch sorted)
// ---------------------------------------------------------------------------
__global__ __launch_bounds__(256) void init_start_k(int* __restrict__ start, int G, int N)
{
    int g = blockIdx.x * 256 + threadIdx.x;
    if (g <= G) start[g] = N;
}

__global__ __launch_bounds__(256) void bound_k(
    const int* __restrict__ batch, int* __restrict__ start, int N)
{
    int n = blockIdx.x * 256 + threadIdx.x;
    if (n >= N) return;
    int b  = batch[n];
    int bp = (n == 0) ? -1 : batch[n - 1];
    for (int g = bp + 1; g <= b; ++g) start[g] = n;
}

__global__ __launch_bounds__(192) void pool_k(
    const ushort* __restrict__ xh, const int* __restrict__ start,
    float* __restrict__ gout, int G)
{
    int g = blockIdx.x;
    int c = threadIdx.x;
    int r0 = start[g], r1 = start[g + 1];
    float s = 0.f;
    for (int r = r0; r < r1; ++r) s += h2f(xh[(size_t)r * HDIM + c]);
    float cnt = (float)(r1 - r0);
    gout[(size_t)g * HDIM + c] = s / fmaxf(cnt, 1.f);
}

// ---------------------------------------------------------------------------
__global__ __launch_bounds__(64) void out_dot_k(
    const float* __restrict__ g2, const float* __restrict__ Wout,
    const float* __restrict__ bout, float* __restrict__ out, int G)
{
    int gi = blockIdx.x;
    int t = threadIdx.x;
    const float* r = g2 + (size_t)gi * HDIM;
    float s = r[t] * Wout[t] + r[t + 64] * Wout[t + 64] + r[t + 128] * Wout[t + 128];
    #pragma unroll
    for (int off = 32; off > 0; off >>= 1) s += __shfl_down(s, off, 64);
    if (t == 0) out[gi] = s + bout[0];
}

// ---------------------------------------------------------------------------
extern "C" void kernel_launch(void* const* d_in, const int* in_sizes, int n_in,
                              void* d_out, int out_size, void* d_ws, size_t ws_size,
                              hipStream_t stream)
{
    const float* x      = (const float*)d_in[0];
    const int*   esrc   = (const int*)d_in[1];
    const int*   edst   = (const int*)d_in[2];
    const int*   batch  = (const int*)d_in[3];
    const float* Wrel0  = (const float*)d_in[4];
    const float* brel0  = (const float*)d_in[5];
    const float* Wroot0 = (const float*)d_in[6];
    const float* Wrel   = (const float*)d_in[7];
    const float* brel   = (const float*)d_in[8];
    const float* Wroot  = (const float*)d_in[9];
    const float* gamma  = (const float*)d_in[10];
    const float* beta   = (const float*)d_in[11];
    const float* Wh1    = (const float*)d_in[12];
    const float* bh1    = (const float*)d_in[13];
    const float* Wh2    = (const float*)d_in[14];
    const float* bh2    = (const float*)d_in[15];
    const float* Wout   = (const float*)d_in[16];
    const float* bout   = (const float*)d_in[17];
    float* out = (float*)d_out;

    const int N  = in_sizes[3];           // 100000
    const int E  = in_sizes[1];           // 400000
    const int K0 = in_sizes[0] / N;       // 32
    const int G  = out_size;              // 2000
    const int nBlocks = (N + 255) / 256;

    char* p = (char*)d_ws;
    auto carve = [&](size_t bytes) -> void* {
        void* r = (void*)p; p += (bytes + 255) & ~(size_t)255; return r;
    };
    float*  bufa  = (float*) carve((size_t)N * HDIM * 4);
    ushort* xh    = (ushort*)carve((size_t)N * HDIM * 2);
    ushort* gh    = (ushort*)carve((size_t)N * HDIM * 2);
    float*  gsum  = (float*) carve((size_t)G * HDIM * 4);
    float*  g1    = (float*) carve((size_t)G * HDIM * 4);
    float*  g2    = (float*) carve((size_t)G * HDIM * 4);
    ushort* gsh   = (ushort*)carve((size_t)G * HDIM * 2);
    ushort* g1h   = (ushort*)carve((size_t)G * HDIM * 2);
    float*  bnsums= (float*) carve(4 * 2 * HDIM * 4);   // per-layer slices
    float*  bnss  = (float*) carve(2 * HDIM * 4);
    float*  degf  = (float*) carve((size_t)N * 4);
    int*    deg   = (int*)   carve((size_t)N * 4);
    int*    row_ptr=(int*)   carve((size_t)(N + 1) * 4);
    int*    cursor= (int*)   carve((size_t)N * 4);
    int*    col   = (int*)   carve((size_t)E * 4);
    int*    bsum  = (int*)   carve((size_t)nBlocks * 4);
    int*    start = (int*)   carve((size_t)(G + 1) * 4);
    ushort* Wrel0f= (ushort*)carve((size_t)K0 * HDIM * 2 * 2);
    ushort* Wroot0f=(ushort*)carve((size_t)K0 * HDIM * 2 * 2);
    ushort* Wrelf = (ushort*)carve((size_t)3 * HDIM * HDIM * 2 * 2);
    ushort* Wrootf= (ushort*)carve((size_t)3 * HDIM * HDIM * 2 * 2);
    ushort* Wh1f  = (ushort*)carve((size_t)HDIM * HDIM * 2 * 2);
    ushort* Wh2f  = (ushort*)carve((size_t)HDIM * HDIM * 2 * 2);

    dim3 b256(256);
    const int eBlocks = (E + 255) / 256;
    const int gemmN = (N + 127) / 128;
    const int gemmG = (G + 127) / 128;

    // ---- weight prep (frag-ordered fp16 hi/lo split)
    {
        int t0 = (K0 >> 5) * 12 * 64;
        int t1 = (HDIM >> 5) * 12 * 64;
        prep_w_k<<<(t0 + 255) / 256, b256, 0, stream>>>(Wrel0,  Wrel0f,  K0, 1);
        prep_w_k<<<(t0 + 255) / 256, b256, 0, stream>>>(Wroot0, Wroot0f, K0, 1);
        prep_w_k<<<(3 * t1 + 255) / 256, b256, 0, stream>>>(Wrel,  Wrelf,  HDIM, 3);
        prep_w_k<<<(3 * t1 + 255) / 256, b256, 0, stream>>>(Wroot, Wrootf, HDIM, 3);
        prep_w_k<<<(t1 + 255) / 256, b256, 0, stream>>>(Wh1, Wh1f, HDIM, 1);
        prep_w_k<<<(t1 + 255) / 256, b256, 0, stream>>>(Wh2, Wh2f, HDIM, 1);
    }
    conv_h_k<<<((N * K0 / 8) + 255) / 256, b256, 0, stream>>>(x, xh, N * K0 / 8);

    // ---- CSR build
    hipMemsetAsync(deg, 0, N * sizeof(int), stream);
    hipMemsetAsync(bnsums, 0, 4 * 2 * HDIM * sizeof(float), stream);
    hist_k<<<eBlocks, b256, 0, stream>>>(edst, deg, E);
    block_sum_k<<<nBlocks, b256, 0, stream>>>(deg, bsum, N);
    scan_bsum_k<<<1, dim3(512), 0, stream>>>(bsum, nBlocks);
    row_ptr_k<<<nBlocks, b256, 0, stream>>>(deg, bsum, row_ptr, cursor, degf, N, E);
    fill_k<<<eBlocks, b256, 0, stream>>>(esrc, edst, cursor, col, E);

    // ---- graph boundaries for pooling
    init_start_k<<<(G + 256) / 256, b256, 0, stream>>>(start, G, N);
    bound_k<<<nBlocks, b256, 0, stream>>>(batch, start, N);

    // ---- layers
    for (int l = 0; l < 4; ++l) {
        const int K = (l == 0) ? K0 : HDIM;
        const ushort* Wrf = (l == 0) ? Wrel0f  : Wrelf  + (size_t)(l - 1) * HDIM * HDIM * 2;
        const ushort* Wtf = (l == 0) ? Wroot0f : Wrootf + (size_t)(l - 1) * HDIM * HDIM * 2;
        const float*  br  = (l == 0) ? brel0   : brel   + (size_t)(l - 1) * HDIM;
        float* stats = bnsums + l * 2 * HDIM;

        int gthreads = N * (K >> 3);
        gather_h_k<<<(gthreads + 255) / 256, b256, 0, stream>>>(
            xh, row_ptr, col, gh, N, K);
        gemm_mfma_k<true, false, true, true><<<gemmN, b256, 0, stream>>>(
            gh, Wrf, xh, Wtf, degf, br, bufa, stats, N, K);
        bn_finalize_k<<<1, dim3(192), 0, stream>>>(stats, gamma + l * HDIM,
                                                   beta + l * HDIM, bnss, 1.0f / N);
        bn_apply_h_k<<<(N * 24 + 255) / 256, b256, 0, stream>>>(bufa, bnss, xh, N);
    }

    // ---- pool
    pool_k<<<G, dim3(192), 0, stream>>>(xh, start, gsum, G);

    // ---- head MLP (MFMA path)
    conv_h_k<<<((G * HDIM / 8) + 255) / 256, b256, 0, stream>>>(gsum, gsh, G * HDIM / 8);
    gemm_mfma_k<false, true, false, false><<<gemmG, b256, 0, stream>>>(
        gsh, Wh1f, nullptr, nullptr, nullptr, bh1, g1, nullptr, G, HDIM);
    conv_h_k<<<((G * HDIM / 8) + 255) / 256, b256, 0, stream>>>(g1, g1h, G * HDIM / 8);
    gemm_mfma_k<false, false, false, false><<<gemmG, b256, 0, stream>>>(
        g1h, Wh2f, nullptr, nullptr, nullptr, bh2, g2, nullptr, G, HDIM);
    out_dot_k<<<G, dim3(64), 0, stream>>>(g2, Wout, bout, out, G);
}

// Round 8
// 772.610 us; speedup vs baseline: 1.4392x; 1.0169x over previous
//
#include <hip/hip_runtime.h>

#define HDIM 192
#define EPS 1e-5f

typedef __attribute__((ext_vector_type(8))) _Float16 half8;
typedef __attribute__((ext_vector_type(4))) float floatx4;

__device__ __forceinline__ float h2f(ushort u) {
    union { ushort u; _Float16 h; } c; c.u = u; return (float)c.h;
}
__device__ __forceinline__ ushort f2h(float x) {
    _Float16 h = (_Float16)x;           // RTN
    union { _Float16 h; ushort u; } c; c.h = h; return c.u;
}
// split fp32 into fp16 hi + fp16 lo (RTN; combined rel err ~2^-22)
__device__ __forceinline__ void splitf(float x, ushort& hi, ushort& lo) {
    hi = f2h(x);
    lo = f2h(x - h2f(hi));
}

// ---------------------------------------------------------------------------
// Weight prep: W[K,192] fp32 (nmat stacked) -> frag-ordered fp16 hi/lo planes.
// Per k-chunk (32 k): [plane(hi,lo)][ct(12)][lane(64)][j(8)] = 12288 ushorts.
// B-frag layout of mfma_f32_16x16x32_f16: n=lane&15, k=(lane>>4)*8+j.
// ---------------------------------------------------------------------------
__global__ __launch_bounds__(256) void prep_w_k(
    const float* __restrict__ W, ushort* __restrict__ Wf, int K, int nmat)
{
    int perMat = (K >> 5) * 12 * 64;
    int idx = blockIdx.x * 256 + threadIdx.x;
    if (idx >= perMat * nmat) return;
    int mat = idx / perMat;
    int r = idx - mat * perMat;
    int lane = r & 63;
    int ct = (r >> 6) % 12;
    int kc = r / (12 * 64);
    int col = ct * 16 + (lane & 15);
    int kb  = kc * 32 + (lane >> 4) * 8;
    const float* Wm = W + (size_t)mat * K * HDIM;
    ushort* base = Wf + (size_t)mat * K * HDIM * 2;
    size_t o = (size_t)kc * 12288 + (size_t)(ct * 64 + lane) * 8;
    #pragma unroll
    for (int j = 0; j < 8; ++j) {
        ushort hi, lo;
        splitf(Wm[(size_t)(kb + j) * HDIM + col], hi, lo);
        base[o + j]        = hi;
        base[o + 6144 + j] = lo;
    }
}

// ---------------------------------------------------------------------------
// convert fp32 array -> single fp16 plane (8 elements per thread, RTN)
// ---------------------------------------------------------------------------
__global__ __launch_bounds__(256) void conv_h_k(
    const float* __restrict__ src, ushort* __restrict__ dst, int n8)
{
    int idx = blockIdx.x * 256 + threadIdx.x;
    if (idx >= n8) return;
    float4 v0 = ((const float4*)src)[idx * 2];
    float4 v1 = ((const float4*)src)[idx * 2 + 1];
    float v[8] = {v0.x, v0.y, v0.z, v0.w, v1.x, v1.y, v1.z, v1.w};
    ushort h[8];
    #pragma unroll
    for (int t = 0; t < 8; ++t) h[t] = f2h(v[t]);
    uint4 ph;
    ph.x = h[0] | ((uint)h[1] << 16); ph.y = h[2] | ((uint)h[3] << 16);
    ph.z = h[4] | ((uint)h[5] << 16); ph.w = h[6] | ((uint)h[7] << 16);
    *(uint4*)(dst + (size_t)idx * 8) = ph;
}

// ---------------------------------------------------------------------------
// MFMA GEMM: C[N,192] = A1@W1 (+ A2@W2) + bias-term, optional fused BN stats.
// Block: 256 thr / 4 waves, tile 64 rows x 192 cols; wave tile 64x48
// (3 ct-tiles) -> acc=48 VGPRs, ~125 total: 4 waves/SIMD occupancy.
// No LDS staging, no K-loop barriers (frag-major B direct from global).
// fp16 2-term: A single plane (RTN), W split hi/lo: Ah*Bh + Ah*Bl.
// ---------------------------------------------------------------------------
template<bool DUAL, bool RELU, bool DEG, bool STATS>
__global__ __launch_bounds__(256, 4) void gemm_mfma_k(
    const ushort* __restrict__ A1h, const ushort* __restrict__ W1f,
    const ushort* __restrict__ A2h, const ushort* __restrict__ W2f,
    const float* __restrict__ degf, const float* __restrict__ bias,
    float* __restrict__ C, float* __restrict__ stats, int N, int K)
{
    __shared__ float sstat[2][HDIM];
    const int tid  = threadIdx.x;
    const int wave = tid >> 6;      // 0..3 = column group (48 cols each)
    const int lane = tid & 63;
    const int row0 = blockIdx.x * 64;
    const int m16 = lane & 15;
    const int g4  = lane >> 4;

    if (STATS && tid < HDIM) { sstat[0][tid] = 0.f; sstat[1][tid] = 0.f; }

    int rowoff[4];
    #pragma unroll
    for (int s = 0; s < 4; ++s) {
        int rr = row0 + s * 16 + m16; if (rr >= N) rr = N - 1;
        rowoff[s] = rr * K;
    }

    floatx4 acc[4][3];
    #pragma unroll
    for (int s = 0; s < 4; ++s)
        #pragma unroll
        for (int ct = 0; ct < 3; ++ct) acc[s][ct] = (floatx4){0.f, 0.f, 0.f, 0.f};

    const int nkc = K >> 5;
    const int nphase = DUAL ? 2 : 1;
    for (int phase = 0; phase < nphase; ++phase) {
        const ushort* Ah = phase ? A2h : A1h;
        const ushort* Wf = phase ? W2f : W1f;
        for (int kc = 0; kc < nkc; ++kc) {
            // B fragments straight from global (frag-major, coalesced, L2-hot)
            const ushort* Wb = Wf + (size_t)kc * 12288 + (size_t)(wave * 3 * 64 + lane) * 8;
            half8 bh[3], bl[3];
            #pragma unroll
            for (int ct = 0; ct < 3; ++ct) {
                bh[ct] = *(const half8*)(Wb + ct * 512);
                bl[ct] = *(const half8*)(Wb + 6144 + ct * 512);
            }
            const int co = kc * 32 + g4 * 8;
            half8 ah[4];
            #pragma unroll
            for (int s = 0; s < 4; ++s)
                ah[s] = *(const half8*)(Ah + rowoff[s] + co);
            #pragma unroll
            for (int ct = 0; ct < 3; ++ct) {
                #pragma unroll
                for (int s = 0; s < 4; ++s) {
                    acc[s][ct] = __builtin_amdgcn_mfma_f32_16x16x32_f16(ah[s], bh[ct], acc[s][ct], 0, 0, 0);
                    acc[s][ct] = __builtin_amdgcn_mfma_f32_16x16x32_f16(ah[s], bl[ct], acc[s][ct], 0, 0, 0);
                }
            }
        }
    }

    if (STATS) __syncthreads();   // sstat zero-init visible

    // epilogue: C/D layout col=lane&15, row=(lane>>4)*4+reg  [m89]
    #pragma unroll
    for (int ct = 0; ct < 3; ++ct) {
        int col = wave * 48 + ct * 16 + m16;
        float bv = bias ? bias[col] : 0.f;
        float lsum = 0.f, lsq = 0.f;
        #pragma unroll
        for (int s = 0; s < 4; ++s) {
            #pragma unroll
            for (int reg = 0; reg < 4; ++reg) {
                int rr = row0 + s * 16 + g4 * 4 + reg;
                if (rr < N) {
                    float v = acc[s][ct][reg] + (DEG ? degf[rr] * bv : bv);
                    if (STATS) { lsum += v; lsq += v * v; }
                    if (RELU) v = fmaxf(v, 0.f);
                    C[(size_t)rr * HDIM + col] = v;
                }
            }
        }
        if (STATS) {
            lsum += __shfl_xor(lsum, 16); lsum += __shfl_xor(lsum, 32);
            lsq  += __shfl_xor(lsq, 16);  lsq  += __shfl_xor(lsq, 32);
            if (g4 == 0) {
                atomicAdd(&sstat[0][col], lsum);
                atomicAdd(&sstat[1][col], lsq);
            }
        }
    }
    if (STATS) {
        __syncthreads();
        if (tid < HDIM) {
            atomicAdd(&stats[tid], sstat[0][tid]);
            atomicAdd(&stats[HDIM + tid], sstat[1][tid]);
        }
    }
}

// ---------------------------------------------------------------------------
// CSR construction from edge_dst
// ---------------------------------------------------------------------------
__global__ __launch_bounds__(256) void hist_k(
    const int* __restrict__ dst, int* __restrict__ deg, int E)
{
    int e = blockIdx.x * 256 + threadIdx.x;
    if (e < E) atomicAdd(&deg[dst[e]], 1);
}

__global__ __launch_bounds__(256) void block_sum_k(
    const int* __restrict__ deg, int* __restrict__ bsum, int N)
{
    __shared__ int s[256];
    int t = threadIdx.x;
    int n = blockIdx.x * 256 + t;
    s[t] = (n < N) ? deg[n] : 0;
    __syncthreads();
    for (int off = 128; off > 0; off >>= 1) {
        if (t < off) s[t] += s[t + off];
        __syncthreads();
    }
    if (t == 0) bsum[blockIdx.x] = s[0];
}

__global__ __launch_bounds__(512) void scan_bsum_k(int* __restrict__ bsum, int nb)
{
    __shared__ int s[512];
    int t = threadIdx.x;
    int v = (t < nb) ? bsum[t] : 0;
    s[t] = v;
    __syncthreads();
    for (int off = 1; off < 512; off <<= 1) {
        int u = (t >= off) ? s[t - off] : 0;
        __syncthreads();
        s[t] += u;
        __syncthreads();
    }
    if (t < nb) bsum[t] = s[t] - v;   // exclusive
}

__global__ __launch_bounds__(256) void row_ptr_k(
    const int* __restrict__ deg, const int* __restrict__ bsum,
    int* __restrict__ row_ptr, int* __restrict__ cursor,
    float* __restrict__ degf, int N, int E)
{
    __shared__ int s[256];
    int t = threadIdx.x;
    int n = blockIdx.x * 256 + t;
    int v = (n < N) ? deg[n] : 0;
    s[t] = v;
    __syncthreads();
    for (int off = 1; off < 256; off <<= 1) {
        int u = (t >= off) ? s[t - off] : 0;
        __syncthreads();
        s[t] += u;
        __syncthreads();
    }
    int ex = s[t] - v + bsum[blockIdx.x];
    if (n < N) {
        row_ptr[n] = ex;
        cursor[n]  = ex;
        degf[n]    = (float)v;
    }
    if (blockIdx.x == 0 && t == 0) row_ptr[N] = E;
}

__global__ __launch_bounds__(256) void fill_k(
    const int* __restrict__ src, const int* __restrict__ dst,
    int* __restrict__ cursor, int* __restrict__ col, int E)
{
    int e = blockIdx.x * 256 + threadIdx.x;
    if (e < E) {
        int p = atomicAdd(&cursor[dst[e]], 1);
        col[p] = src[e];
    }
}

// ---------------------------------------------------------------------------
// gather on fp16 plane: g[n] = sum_{j} x[col[j]]; fp32 accumulate, RTN out.
// ---------------------------------------------------------------------------
__global__ __launch_bounds__(256) void gather_h_k(
    const ushort* __restrict__ xh, const int* __restrict__ row_ptr,
    const int* __restrict__ col, ushort* __restrict__ gh, int N, int K)
{
    int WQ = K >> 3;
    int idx = blockIdx.x * 256 + threadIdx.x;
    if (idx >= N * WQ) return;
    int n = idx / WQ;
    int q = (idx - n * WQ) * 8;
    int j0 = row_ptr[n], j1 = row_ptr[n + 1];
    float acc[8] = {0.f,0.f,0.f,0.f,0.f,0.f,0.f,0.f};
    for (int j = j0; j < j1; ++j) {
        int s = col[j];
        uint4 hv = *(const uint4*)(xh + (size_t)s * K + q);
        uint hu[4] = {hv.x, hv.y, hv.z, hv.w};
        #pragma unroll
        for (int t = 0; t < 4; ++t) {
            acc[2*t]   += h2f((ushort)(hu[t] & 0xffffu));
            acc[2*t+1] += h2f((ushort)(hu[t] >> 16));
        }
    }
    ushort oh[8];
    #pragma unroll
    for (int t = 0; t < 8; ++t) oh[t] = f2h(acc[t]);
    uint4 ph;
    ph.x = oh[0] | ((uint)oh[1] << 16); ph.y = oh[2] | ((uint)oh[3] << 16);
    ph.z = oh[4] | ((uint)oh[5] << 16); ph.w = oh[6] | ((uint)oh[7] << 16);
    *(uint4*)(gh + (size_t)n * K + q) = ph;
}

// ---------------------------------------------------------------------------
// batchnorm finalize + apply (single fp16 plane out)
// ---------------------------------------------------------------------------
__global__ void bn_finalize_k(const float* __restrict__ sums,
                              const float* __restrict__ gamma,
                              const float* __restrict__ beta,
                              float* __restrict__ ss, float invN)
{
    int c = threadIdx.x;
    float mu  = sums[c] * invN;
    float var = sums[HDIM + c] * invN - mu * mu;
    float sc  = gamma[c] * rsqrtf(var + EPS);
    ss[c]        = sc;
    ss[HDIM + c] = beta[c] - mu * sc;
}

__global__ __launch_bounds__(256) void bn_apply_h_k(
    const float* __restrict__ h, const float* __restrict__ ss,
    ushort* __restrict__ xh, int N)
{
    int idx = blockIdx.x * 256 + threadIdx.x;   // over N*24
    if (idx >= N * 24) return;
    int q = (idx % 24) * 8;
    float4 v0 = ((const float4*)h)[idx * 2];
    float4 v1 = ((const float4*)h)[idx * 2 + 1];
    float v[8] = {v0.x, v0.y, v0.z, v0.w, v1.x, v1.y, v1.z, v1.w};
    ushort oh[8];
    #pragma unroll
    for (int t = 0; t < 8; ++t) {
        float r = fmaxf(v[t] * ss[q + t] + ss[HDIM + q + t], 0.f);
        oh[t] = f2h(r);
    }
    uint4 ph;
    ph.x = oh[0] | ((uint)oh[1] << 16); ph.y = oh[2] | ((uint)oh[3] << 16);
    ph.z = oh[4] | ((uint)oh[5] << 16); ph.w = oh[6] | ((uint)oh[7] << 16);
    *(uint4*)(xh + (size_t)idx * 8) = ph;
}

// ---------------------------------------------------------------------------
// pool over contiguous per-graph row ranges (batch sorted)
// ---------------------------------------------------------------------------
__global__ __launch_bounds__(256) void init_start_k(int* __restrict__ start, int G, int N)
{
    int g = blockIdx.x * 256 + threadIdx.x;
    if (g <= G) start[g] = N;
}

__global__ __launch_bounds__(256) void bound_k(
    const int* __restrict__ batch, int* __restrict__ start, int N)
{
    int n = blockIdx.x * 256 + threadIdx.x;
    if (n >= N) return;
    int b  = batch[n];
    int bp = (n == 0) ? -1 : batch[n - 1];
    for (int g = bp + 1; g <= b; ++g) start[g] = n;
}

__global__ __launch_bounds__(192) void pool_k(
    const ushort* __restrict__ xh, const int* __restrict__ start,
    float* __restrict__ gout, int G)
{
    int g = blockIdx.x;
    int c = threadIdx.x;
    int r0 = start[g], r1 = start[g + 1];
    float s = 0.f;
    for (int r = r0; r < r1; ++r) s += h2f(xh[(size_t)r * HDIM + c]);
    float cnt = (float)(r1 - r0);
    gout[(size_t)g * HDIM + c] = s / fmaxf(cnt, 1.f);
}

// ---------------------------------------------------------------------------
__global__ __launch_bounds__(64) void out_dot_k(
    const float* __restrict__ g2, const float* __restrict__ Wout,
    const float* __restrict__ bout, float* __restrict__ out, int G)
{
    int gi = blockIdx.x;
    int t = threadIdx.x;
    const float* r = g2 + (size_t)gi * HDIM;
    float s = r[t] * Wout[t] + r[t + 64] * Wout[t + 64] + r[t + 128] * Wout[t + 128];
    #pragma unroll
    for (int off = 32; off > 0; off >>= 1) s += __shfl_down(s, off, 64);
    if (t == 0) out[gi] = s + bout[0];
}

// ---------------------------------------------------------------------------
extern "C" void kernel_launch(void* const* d_in, const int* in_sizes, int n_in,
                              void* d_out, int out_size, void* d_ws, size_t ws_size,
                              hipStream_t stream)
{
    const float* x      = (const float*)d_in[0];
    const int*   esrc   = (const int*)d_in[1];
    const int*   edst   = (const int*)d_in[2];
    const int*   batch  = (const int*)d_in[3];
    const float* Wrel0  = (const float*)d_in[4];
    const float* brel0  = (const float*)d_in[5];
    const float* Wroot0 = (const float*)d_in[6];
    const float* Wrel   = (const float*)d_in[7];
    const float* brel   = (const float*)d_in[8];
    const float* Wroot  = (const float*)d_in[9];
    const float* gamma  = (const float*)d_in[10];
    const float* beta   = (const float*)d_in[11];
    const float* Wh1    = (const float*)d_in[12];
    const float* bh1    = (const float*)d_in[13];
    const float* Wh2    = (const float*)d_in[14];
    const float* bh2    = (const float*)d_in[15];
    const float* Wout   = (const float*)d_in[16];
    const float* bout   = (const float*)d_in[17];
    float* out = (float*)d_out;

    const int N  = in_sizes[3];           // 100000
    const int E  = in_sizes[1];           // 400000
    const int K0 = in_sizes[0] / N;       // 32
    const int G  = out_size;              // 2000
    const int nBlocks = (N + 255) / 256;

    char* p = (char*)d_ws;
    auto carve = [&](size_t bytes) -> void* {
        void* r = (void*)p; p += (bytes + 255) & ~(size_t)255; return r;
    };
    float*  bufa  = (float*) carve((size_t)N * HDIM * 4);
    ushort* xh    = (ushort*)carve((size_t)N * HDIM * 2);
    ushort* gh    = (ushort*)carve((size_t)N * HDIM * 2);
    float*  gsum  = (float*) carve((size_t)G * HDIM * 4);
    float*  g1    = (float*) carve((size_t)G * HDIM * 4);
    float*  g2    = (float*) carve((size_t)G * HDIM * 4);
    ushort* gsh   = (ushort*)carve((size_t)G * HDIM * 2);
    ushort* g1h   = (ushort*)carve((size_t)G * HDIM * 2);
    float*  bnsums= (float*) carve(4 * 2 * HDIM * 4);   // per-layer slices
    float*  bnss  = (float*) carve(2 * HDIM * 4);
    float*  degf  = (float*) carve((size_t)N * 4);
    int*    deg   = (int*)   carve((size_t)N * 4);
    int*    row_ptr=(int*)   carve((size_t)(N + 1) * 4);
    int*    cursor= (int*)   carve((size_t)N * 4);
    int*    col   = (int*)   carve((size_t)E * 4);
    int*    bsum  = (int*)   carve((size_t)nBlocks * 4);
    int*    start = (int*)   carve((size_t)(G + 1) * 4);
    ushort* Wrel0f= (ushort*)carve((size_t)K0 * HDIM * 2 * 2);
    ushort* Wroot0f=(ushort*)carve((size_t)K0 * HDIM * 2 * 2);
    ushort* Wrelf = (ushort*)carve((size_t)3 * HDIM * HDIM * 2 * 2);
    ushort* Wrootf= (ushort*)carve((size_t)3 * HDIM * HDIM * 2 * 2);
    ushort* Wh1f  = (ushort*)carve((size_t)HDIM * HDIM * 2 * 2);
    ushort* Wh2f  = (ushort*)carve((size_t)HDIM * HDIM * 2 * 2);

    dim3 b256(256);
    const int eBlocks = (E + 255) / 256;
    const int gemmN = (N + 63) / 64;
    const int gemmG = (G + 63) / 64;

    // ---- weight prep (frag-ordered fp16 hi/lo split)
    {
        int t0 = (K0 >> 5) * 12 * 64;
        int t1 = (HDIM >> 5) * 12 * 64;
        prep_w_k<<<(t0 + 255) / 256, b256, 0, stream>>>(Wrel0,  Wrel0f,  K0, 1);
        prep_w_k<<<(t0 + 255) / 256, b256, 0, stream>>>(Wroot0, Wroot0f, K0, 1);
        prep_w_k<<<(3 * t1 + 255) / 256, b256, 0, stream>>>(Wrel,  Wrelf,  HDIM, 3);
        prep_w_k<<<(3 * t1 + 255) / 256, b256, 0, stream>>>(Wroot, Wrootf, HDIM, 3);
        prep_w_k<<<(t1 + 255) / 256, b256, 0, stream>>>(Wh1, Wh1f, HDIM, 1);
        prep_w_k<<<(t1 + 255) / 256, b256, 0, stream>>>(Wh2, Wh2f, HDIM, 1);
    }
    conv_h_k<<<((N * K0 / 8) + 255) / 256, b256, 0, stream>>>(x, xh, N * K0 / 8);

    // ---- CSR build
    hipMemsetAsync(deg, 0, N * sizeof(int), stream);
    hipMemsetAsync(bnsums, 0, 4 * 2 * HDIM * sizeof(float), stream);
    hist_k<<<eBlocks, b256, 0, stream>>>(edst, deg, E);
    block_sum_k<<<nBlocks, b256, 0, stream>>>(deg, bsum, N);
    scan_bsum_k<<<1, dim3(512), 0, stream>>>(bsum, nBlocks);
    row_ptr_k<<<nBlocks, b256, 0, stream>>>(deg, bsum, row_ptr, cursor, degf, N, E);
    fill_k<<<eBlocks, b256, 0, stream>>>(esrc, edst, cursor, col, E);

    // ---- graph boundaries for pooling
    init_start_k<<<(G + 256) / 256, b256, 0, stream>>>(start, G, N);
    bound_k<<<nBlocks, b256, 0, stream>>>(batch, start, N);

    // ---- layers
    for (int l = 0; l < 4; ++l) {
        const int K = (l == 0) ? K0 : HDIM;
        const ushort* Wrf = (l == 0) ? Wrel0f  : Wrelf  + (size_t)(l - 1) * HDIM * HDIM * 2;
        const ushort* Wtf = (l == 0) ? Wroot0f : Wrootf + (size_t)(l - 1) * HDIM * HDIM * 2;
        const float*  br  = (l == 0) ? brel0   : brel   + (size_t)(l - 1) * HDIM;
        float* stats = bnsums + l * 2 * HDIM;

        int gthreads = N * (K >> 3);
        gather_h_k<<<(gthreads + 255) / 256, b256, 0, stream>>>(
            xh, row_ptr, col, gh, N, K);
        gemm_mfma_k<true, false, true, true><<<gemmN, b256, 0, stream>>>(
            gh, Wrf, xh, Wtf, degf, br, bufa, stats, N, K);
        bn_finalize_k<<<1, dim3(192), 0, stream>>>(stats, gamma + l * HDIM,
                                                   beta + l * HDIM, bnss, 1.0f / N);
        bn_apply_h_k<<<(N * 24 + 255) / 256, b256, 0, stream>>>(bufa, bnss, xh, N);
    }

    // ---- pool
    pool_k<<<G, dim3(192), 0, stream>>>(xh, start, gsum, G);

    // ---- head MLP (MFMA path)
    conv_h_k<<<((G * HDIM / 8) + 255) / 256, b256, 0, stream>>>(gsum, gsh, G * HDIM / 8);
    gemm_mfma_k<false, true, false, false><<<gemmG, b256, 0, stream>>>(
        gsh, Wh1f, nullptr, nullptr, nullptr, bh1, g1, nullptr, G, HDIM);
    conv_h_k<<<((G * HDIM / 8) + 255) / 256, b256, 0, stream>>>(g1, g1h, G * HDIM / 8);
    gemm_mfma_k<false, false, false, false><<<gemmG, b256, 0, stream>>>(
        g1h, Wh2f, nullptr, nullptr, nullptr, bh2, g2, nullptr, G, HDIM);
    out_dot_k<<<G, dim3(64), 0, stream>>>(g2, Wout, bout, out, G);
}